// Round 1
// baseline (895.433 us; speedup 1.0000x reference)
//
#include <hip/hip_runtime.h>
#include <math.h>

#define N_    16
#define C_    512
#define HW_   1024
#define CE_   768
#define S_    77
#define NH_   8
#define D_    64
#define FEATS_ 512
#define EPS_  1e-5f

// workspace layout (float offsets)
#define WS_STATS 0                      // 32 floats (sum, sumsq per sample)
#define WS_ALPHA 1024                   // 16*512
#define WS_BETA  (WS_ALPHA + 8192)      // 16*512
#define WS_QBIAS (WS_BETA + 8192)       // 16*512
#define WS_K     32768                  // 16*8*77*64 = 630784
#define WS_V     (WS_K + 630784)
#define WS_Q     (WS_V + 630784)        // 16*512*1024 = 8388608 (q, overwritten by y)

// ---------------- per-sample mean/var partial sums ----------------
__global__ __launch_bounds__(256) void stats_kernel(const float* __restrict__ inp,
                                                    float* __restrict__ stats) {
    int n = blockIdx.x >> 4;
    int slice = blockIdx.x & 15;
    const float* base = inp + (size_t)n * C_ * HW_ + slice * (C_ * HW_ / 16);
    float s = 0.f, s2 = 0.f;
    const float4* b4 = (const float4*)base;
    for (int i = threadIdx.x; i < (C_ * HW_ / 16) / 4; i += 256) {
        float4 v = b4[i];
        s  += v.x + v.y + v.z + v.w;
        s2 += v.x * v.x + v.y * v.y + v.z * v.z + v.w * v.w;
    }
    for (int off = 32; off; off >>= 1) {
        s  += __shfl_down(s, off);
        s2 += __shfl_down(s2, off);
    }
    __shared__ float sh[8];
    int wid = threadIdx.x >> 6, lane = threadIdx.x & 63;
    if (lane == 0) { sh[wid] = s; sh[4 + wid] = s2; }
    __syncthreads();
    if (threadIdx.x == 0) {
        atomicAdd(&stats[2 * n], sh[0] + sh[1] + sh[2] + sh[3]);
        atomicAdd(&stats[2 * n + 1], sh[4] + sh[5] + sh[6] + sh[7]);
    }
}

// ---------------- ss = cond @ adagn_w.T + adagn_b; fold norm -> alpha,beta ----------------
__global__ __launch_bounds__(512) void alphabeta_kernel(const float* __restrict__ cond,
                                                        const float* __restrict__ agw,
                                                        const float* __restrict__ agb,
                                                        const float* __restrict__ stats,
                                                        float* __restrict__ alpha,
                                                        float* __restrict__ beta) {
    int n = blockIdx.x;
    __shared__ float cs[FEATS_];
    for (int i = threadIdx.x; i < FEATS_; i += blockDim.x) cs[i] = cond[n * FEATS_ + i];
    __syncthreads();
    int c = threadIdx.x;   // 0..511
    float sc = agb[c], sh = agb[C_ + c];
    const float4* w1 = (const float4*)(agw + (size_t)c * FEATS_);
    const float4* w2 = (const float4*)(agw + (size_t)(C_ + c) * FEATS_);
    const float4* cv = (const float4*)cs;
    for (int i = 0; i < FEATS_ / 4; i++) {
        float4 a = w1[i], b = w2[i], cc = cv[i];
        sc += a.x * cc.x + a.y * cc.y + a.z * cc.z + a.w * cc.w;
        sh += b.x * cc.x + b.y * cc.y + b.z * cc.z + b.w * cc.w;
    }
    float cnt = (float)(C_ * HW_);
    float mu  = stats[2 * n] / cnt;
    float var = stats[2 * n + 1] / cnt - mu * mu;
    float rstd = rsqrtf(var + EPS_);
    float al = rstd * (sc + 1.f);
    alpha[n * C_ + c] = al;
    beta[n * C_ + c]  = sh - mu * al;
}

// ---------------- effective q bias: q_b[o] + sum_c q_w[o][c]*beta[n][c] ----------------
__global__ __launch_bounds__(512) void qbias_kernel(const float* __restrict__ qw,
                                                    const float* __restrict__ qb,
                                                    const float* __restrict__ beta,
                                                    float* __restrict__ qbias) {
    int n = blockIdx.x;
    __shared__ float bs[C_];
    for (int i = threadIdx.x; i < C_; i += blockDim.x) bs[i] = beta[n * C_ + i];
    __syncthreads();
    int o = threadIdx.x;
    float acc = qb[o];
    const float4* w  = (const float4*)(qw + (size_t)o * C_);
    const float4* bv = (const float4*)bs;
    for (int i = 0; i < C_ / 4; i++) {
        float4 a = w[i], b = bv[i];
        acc += a.x * b.x + a.y * b.y + a.z * b.z + a.w * b.w;
    }
    qbias[n * C_ + o] = acc;
}

// ---------------- Q = (qw * alpha) @ input + qbias ; tiled fp32 GEMM ----------------
__global__ __launch_bounds__(256) void gemm_q_kernel(const float* __restrict__ Aw,
                                                     const float* __restrict__ inp,
                                                     const float* __restrict__ alpha,
                                                     const float* __restrict__ qbias,
                                                     float* __restrict__ outq) {
    int n  = blockIdx.z;
    int o0 = blockIdx.y * 64;
    int s0 = blockIdx.x * 64;
    const float* B  = inp + (size_t)n * C_ * HW_;
    const float* al = alpha + n * C_;
    __shared__ float As[16][64];
    __shared__ float Bs[16][68];
    int tid = threadIdx.x;
    int am = tid >> 2, ak = (tid & 3) << 2;
    int bk = tid >> 4, bs = (tid & 15) << 2;
    int tm = tid >> 4, tn = tid & 15;
    float acc[4][4] = {};
    for (int kt = 0; kt < C_ / 16; ++kt) {
        int k0 = kt * 16;
        float4 a4 = *(const float4*)(Aw + (size_t)(o0 + am) * C_ + k0 + ak);
        a4.x *= al[k0 + ak]; a4.y *= al[k0 + ak + 1];
        a4.z *= al[k0 + ak + 2]; a4.w *= al[k0 + ak + 3];
        float4 b4 = *(const float4*)(B + (size_t)(k0 + bk) * HW_ + s0 + bs);
        __syncthreads();
        As[ak + 0][am] = a4.x; As[ak + 1][am] = a4.y;
        As[ak + 2][am] = a4.z; As[ak + 3][am] = a4.w;
        *(float4*)&Bs[bk][bs] = b4;
        __syncthreads();
#pragma unroll
        for (int k = 0; k < 16; k++) {
            float4 av = *(const float4*)&As[k][tm * 4];
            float4 bv = *(const float4*)&Bs[k][tn * 4];
            acc[0][0] = fmaf(av.x, bv.x, acc[0][0]); acc[0][1] = fmaf(av.x, bv.y, acc[0][1]);
            acc[0][2] = fmaf(av.x, bv.z, acc[0][2]); acc[0][3] = fmaf(av.x, bv.w, acc[0][3]);
            acc[1][0] = fmaf(av.y, bv.x, acc[1][0]); acc[1][1] = fmaf(av.y, bv.y, acc[1][1]);
            acc[1][2] = fmaf(av.y, bv.z, acc[1][2]); acc[1][3] = fmaf(av.y, bv.w, acc[1][3]);
            acc[2][0] = fmaf(av.z, bv.x, acc[2][0]); acc[2][1] = fmaf(av.z, bv.y, acc[2][1]);
            acc[2][2] = fmaf(av.z, bv.z, acc[2][2]); acc[2][3] = fmaf(av.z, bv.w, acc[2][3]);
            acc[3][0] = fmaf(av.w, bv.x, acc[3][0]); acc[3][1] = fmaf(av.w, bv.y, acc[3][1]);
            acc[3][2] = fmaf(av.w, bv.z, acc[3][2]); acc[3][3] = fmaf(av.w, bv.w, acc[3][3]);
        }
    }
#pragma unroll
    for (int i = 0; i < 4; i++) {
        int row = o0 + tm * 4 + i;
        float qbv = qbias[n * C_ + row];
        float4 r;
        r.x = acc[i][0] + qbv; r.y = acc[i][1] + qbv;
        r.z = acc[i][2] + qbv; r.w = acc[i][3] + qbv;
        *(float4*)(outq + ((size_t)n * C_ + row) * HW_ + s0 + tn * 4) = r;
    }
}

// ---------------- out = input + out_w @ y + out_b ----------------
__global__ __launch_bounds__(256) void gemm_out_kernel(const float* __restrict__ Aw,
                                                       const float* __restrict__ y,
                                                       const float* __restrict__ inp,
                                                       const float* __restrict__ ob,
                                                       float* __restrict__ outp) {
    int n  = blockIdx.z;
    int o0 = blockIdx.y * 64;
    int s0 = blockIdx.x * 64;
    const float* B = y + (size_t)n * C_ * HW_;
    __shared__ float As[16][64];
    __shared__ float Bs[16][68];
    int tid = threadIdx.x;
    int am = tid >> 2, ak = (tid & 3) << 2;
    int bk = tid >> 4, bs = (tid & 15) << 2;
    int tm = tid >> 4, tn = tid & 15;
    float acc[4][4] = {};
    for (int kt = 0; kt < C_ / 16; ++kt) {
        int k0 = kt * 16;
        float4 a4 = *(const float4*)(Aw + (size_t)(o0 + am) * C_ + k0 + ak);
        float4 b4 = *(const float4*)(B + (size_t)(k0 + bk) * HW_ + s0 + bs);
        __syncthreads();
        As[ak + 0][am] = a4.x; As[ak + 1][am] = a4.y;
        As[ak + 2][am] = a4.z; As[ak + 3][am] = a4.w;
        *(float4*)&Bs[bk][bs] = b4;
        __syncthreads();
#pragma unroll
        for (int k = 0; k < 16; k++) {
            float4 av = *(const float4*)&As[k][tm * 4];
            float4 bv = *(const float4*)&Bs[k][tn * 4];
            acc[0][0] = fmaf(av.x, bv.x, acc[0][0]); acc[0][1] = fmaf(av.x, bv.y, acc[0][1]);
            acc[0][2] = fmaf(av.x, bv.z, acc[0][2]); acc[0][3] = fmaf(av.x, bv.w, acc[0][3]);
            acc[1][0] = fmaf(av.y, bv.x, acc[1][0]); acc[1][1] = fmaf(av.y, bv.y, acc[1][1]);
            acc[1][2] = fmaf(av.y, bv.z, acc[1][2]); acc[1][3] = fmaf(av.y, bv.w, acc[1][3]);
            acc[2][0] = fmaf(av.z, bv.x, acc[2][0]); acc[2][1] = fmaf(av.z, bv.y, acc[2][1]);
            acc[2][2] = fmaf(av.z, bv.z, acc[2][2]); acc[2][3] = fmaf(av.z, bv.w, acc[2][3]);
            acc[3][0] = fmaf(av.w, bv.x, acc[3][0]); acc[3][1] = fmaf(av.w, bv.y, acc[3][1]);
            acc[3][2] = fmaf(av.w, bv.z, acc[3][2]); acc[3][3] = fmaf(av.w, bv.w, acc[3][3]);
        }
    }
#pragma unroll
    for (int i = 0; i < 4; i++) {
        int row = o0 + tm * 4 + i;
        float bias = ob[row];
        size_t idx = ((size_t)n * C_ + row) * HW_ + s0 + tn * 4;
        float4 res = *(const float4*)(inp + idx);
        float4 r;
        r.x = acc[i][0] + bias + res.x; r.y = acc[i][1] + bias + res.y;
        r.z = acc[i][2] + bias + res.z; r.w = acc[i][3] + bias + res.w;
        *(float4*)(outp + idx) = r;
    }
}

// ---------------- layernorm(enc) then kv projection, scattered to k/v ----------------
__global__ __launch_bounds__(256) void lnkv_kernel(const float* __restrict__ enc,
                                                   const float* __restrict__ lnw,
                                                   const float* __restrict__ lnb,
                                                   const float* __restrict__ kvw,
                                                   const float* __restrict__ kvb,
                                                   float* __restrict__ kbuf,
                                                   float* __restrict__ vbuf) {
    int n = blockIdx.x / S_;
    int s = blockIdx.x % S_;
    const float* row = enc + ((size_t)n * S_ + s) * CE_;
    __shared__ float e[CE_];
    int t = threadIdx.x;
    float v0 = row[t], v1 = row[t + 256], v2 = row[t + 512];
    float sum = v0 + v1 + v2;
    float sq  = v0 * v0 + v1 * v1 + v2 * v2;
    for (int off = 32; off; off >>= 1) {
        sum += __shfl_down(sum, off);
        sq  += __shfl_down(sq, off);
    }
    __shared__ float red[8];
    int wid = t >> 6, lane = t & 63;
    if (lane == 0) { red[wid] = sum; red[4 + wid] = sq; }
    __syncthreads();
    float tot = red[0] + red[1] + red[2] + red[3];
    float tsq = red[4] + red[5] + red[6] + red[7];
    float mu  = tot / CE_;
    float var = tsq / CE_ - mu * mu;
    float rstd = rsqrtf(var + EPS_);
    e[t]       = (v0 - mu) * rstd * lnw[t] + lnb[t];
    e[t + 256] = (v1 - mu) * rstd * lnw[t + 256] + lnb[t + 256];
    e[t + 512] = (v2 - mu) * rstd * lnw[t + 512] + lnb[t + 512];
    __syncthreads();
    const float4* ev = (const float4*)e;
#pragma unroll
    for (int i = 0; i < 4; i++) {
        int j = t + i * 256;
        float acc = kvb[j];
        const float4* w = (const float4*)(kvw + (size_t)j * CE_);
        for (int u = 0; u < CE_ / 4; u++) {
            float4 a = w[u], b = ev[u];
            acc += a.x * b.x + a.y * b.y + a.z * b.z + a.w * b.w;
        }
        int h16 = j >> 6, dd = j & 63;
        if (h16 < NH_)
            kbuf[(((size_t)n * NH_ + h16) * S_ + s) * D_ + dd] = acc;
        else
            vbuf[(((size_t)n * NH_ + (h16 - NH_)) * S_ + s) * D_ + dd] = acc;
    }
}

// ---------------- attention: reads Q buffer, overwrites it with Y in place ----------------
__global__ __launch_bounds__(256) void attn_kernel(const float* __restrict__ kbuf,
                                                   const float* __restrict__ vbuf,
                                                   const float* __restrict__ mask,
                                                   float* __restrict__ qy) {
    int nh = blockIdx.x;          // n*8 + h
    int n = nh >> 3, h = nh & 7;
    int qpos = blockIdx.y * 256 + threadIdx.x;
    __shared__ float kl[S_ * D_];
    __shared__ float vl[S_ * D_];
    __shared__ float msk[S_ + 3];
    const float4* ksrc = (const float4*)(kbuf + (size_t)nh * S_ * D_);
    const float4* vsrc = (const float4*)(vbuf + (size_t)nh * S_ * D_);
    for (int i = threadIdx.x; i < S_ * D_ / 4; i += 256) {
        ((float4*)kl)[i] = ksrc[i];
        ((float4*)vl)[i] = vsrc[i];
    }
    for (int i = threadIdx.x; i < S_; i += 256) msk[i] = mask[n * S_ + i] * 10000.f;
    __syncthreads();

    float* qb = qy + ((size_t)n * C_ + h * D_) * HW_ + qpos;
    float4 qv[16];
#pragma unroll
    for (int d = 0; d < D_; d++) ((float*)qv)[d] = qb[(size_t)d * HW_];

    float m = -1e30f, l = 0.f;
    float4 ya[16];
#pragma unroll
    for (int d4 = 0; d4 < 16; d4++) ya[d4] = make_float4(0.f, 0.f, 0.f, 0.f);

    for (int j = 0; j < S_; j++) {
        const float4* kr = (const float4*)&kl[j * D_];
        float dot = 0.f;
#pragma unroll
        for (int d4 = 0; d4 < 16; d4++) {
            float4 kk = kr[d4];
            dot = fmaf(qv[d4].x, kk.x, dot);
            dot = fmaf(qv[d4].y, kk.y, dot);
            dot = fmaf(qv[d4].z, kk.z, dot);
            dot = fmaf(qv[d4].w, kk.w, dot);
        }
        float sc = dot * 0.125f - msk[j];
        if (sc > m) {
            float corr = __expf(m - sc);
            l *= corr;
#pragma unroll
            for (int d4 = 0; d4 < 16; d4++) {
                ya[d4].x *= corr; ya[d4].y *= corr;
                ya[d4].z *= corr; ya[d4].w *= corr;
            }
            m = sc;
        }
        float p = __expf(sc - m);
        l += p;
        const float4* vr = (const float4*)&vl[j * D_];
#pragma unroll
        for (int d4 = 0; d4 < 16; d4++) {
            float4 vv = vr[d4];
            ya[d4].x = fmaf(p, vv.x, ya[d4].x);
            ya[d4].y = fmaf(p, vv.y, ya[d4].y);
            ya[d4].z = fmaf(p, vv.z, ya[d4].z);
            ya[d4].w = fmaf(p, vv.w, ya[d4].w);
        }
    }
    float inv = 1.f / l;
#pragma unroll
    for (int d = 0; d < D_; d++) qb[(size_t)d * HW_] = ((float*)ya)[d] * inv;
}

extern "C" void kernel_launch(void* const* d_in, const int* in_sizes, int n_in,
                              void* d_out, int out_size, void* d_ws, size_t ws_size,
                              hipStream_t stream) {
    const float* inp  = (const float*)d_in[0];
    const float* cond = (const float*)d_in[1];
    const float* enc  = (const float*)d_in[2];
    const float* mask = (const float*)d_in[3];
    const float* agw  = (const float*)d_in[4];
    const float* agb  = (const float*)d_in[5];
    const float* lnw  = (const float*)d_in[6];
    const float* lnb  = (const float*)d_in[7];
    const float* qw   = (const float*)d_in[8];
    const float* qb   = (const float*)d_in[9];
    const float* kvw  = (const float*)d_in[10];
    const float* kvb  = (const float*)d_in[11];
    const float* ow   = (const float*)d_in[12];
    const float* ob   = (const float*)d_in[13];
    float* ws  = (float*)d_ws;
    float* out = (float*)d_out;

    hipMemsetAsync(ws + WS_STATS, 0, 32 * sizeof(float), stream);
    stats_kernel<<<dim3(N_ * 16), 256, 0, stream>>>(inp, ws + WS_STATS);
    alphabeta_kernel<<<N_, 512, 0, stream>>>(cond, agw, agb, ws + WS_STATS,
                                             ws + WS_ALPHA, ws + WS_BETA);
    qbias_kernel<<<N_, 512, 0, stream>>>(qw, qb, ws + WS_BETA, ws + WS_QBIAS);
    gemm_q_kernel<<<dim3(16, 8, N_), 256, 0, stream>>>(qw, inp, ws + WS_ALPHA,
                                                       ws + WS_QBIAS, ws + WS_Q);
    lnkv_kernel<<<N_ * S_, 256, 0, stream>>>(enc, lnw, lnb, kvw, kvb,
                                             ws + WS_K, ws + WS_V);
    attn_kernel<<<dim3(N_ * NH_, HW_ / 256), 256, 0, stream>>>(ws + WS_K, ws + WS_V,
                                                               mask, ws + WS_Q);
    gemm_out_kernel<<<dim3(16, 8, N_), 256, 0, stream>>>(ow, ws + WS_Q, inp, ob, out);
}

// Round 3
// 263.564 us; speedup vs baseline: 3.3974x; 3.3974x over previous
//
#include <hip/hip_runtime.h>
#include <math.h>

typedef unsigned short u16;
typedef __bf16 bf16x8 __attribute__((ext_vector_type(8)));
typedef float f32x4 __attribute__((ext_vector_type(4)));

#define AS1 __attribute__((address_space(1)))
#define AS3 __attribute__((address_space(3)))

#define N_    16
#define C_    512
#define HW_   1024
#define CE_   768
#define S_    77
#define NH_   8
#define D_    64
#define FEATS_ 512
#define EPS_  1e-5f
#define TOK_  (N_ * S_)   // 1232

// fp32 workspace (float offsets)
#define WS_STATS 0
#define WS_ALPHA 1024
#define WS_BETA  (WS_ALPHA + 8192)
#define WS_QBIAS (WS_BETA + 8192)
// u16 (bf16) workspace, base at byte 131072
#define WSU_BYTE 131072
#define U_QW  0
#define U_OW  262144
#define U_KVW 524288
#define U_EB  1310720              // 1232*768   = 946176
#define U_KVB 2256896              // 1232*1024  = 1261568
#define U_QT  3518464              // 16*1024*512= 8388608
#define U_XT  11907072             // xT, later reused as yT (attn writes after gemm_q consumed xT)

__device__ __forceinline__ u16 f2bf(float f) {
    unsigned u = __float_as_uint(f);
    return (u16)((u + 0x7FFFu + ((u >> 16) & 1u)) >> 16);
}
__device__ __forceinline__ float bf2f(u16 h) {
    return __uint_as_float(((unsigned)h) << 16);
}

// ---------------- per-sample mean/var partial sums ----------------
__global__ __launch_bounds__(256) void stats_kernel(const float* __restrict__ inp,
                                                    float* __restrict__ stats) {
    int n = blockIdx.x >> 4;
    int slice = blockIdx.x & 15;
    const float* base = inp + (size_t)n * C_ * HW_ + slice * (C_ * HW_ / 16);
    float s = 0.f, s2 = 0.f;
    const float4* b4 = (const float4*)base;
    for (int i = threadIdx.x; i < (C_ * HW_ / 16) / 4; i += 256) {
        float4 v = b4[i];
        s  += v.x + v.y + v.z + v.w;
        s2 += v.x * v.x + v.y * v.y + v.z * v.z + v.w * v.w;
    }
    for (int off = 32; off; off >>= 1) {
        s  += __shfl_down(s, off);
        s2 += __shfl_down(s2, off);
    }
    __shared__ float sh[8];
    int wid = threadIdx.x >> 6, lane = threadIdx.x & 63;
    if (lane == 0) { sh[wid] = s; sh[4 + wid] = s2; }
    __syncthreads();
    if (threadIdx.x == 0) {
        atomicAdd(&stats[2 * n], sh[0] + sh[1] + sh[2] + sh[3]);
        atomicAdd(&stats[2 * n + 1], sh[4] + sh[5] + sh[6] + sh[7]);
    }
}

// ---------------- fold instance-norm + AdaGN -> alpha, beta ----------------
__global__ __launch_bounds__(512) void alphabeta_kernel(const float* __restrict__ cond,
                                                        const float* __restrict__ agw,
                                                        const float* __restrict__ agb,
                                                        const float* __restrict__ stats,
                                                        float* __restrict__ alpha,
                                                        float* __restrict__ beta) {
    int n = blockIdx.x;
    __shared__ float cs[FEATS_];
    for (int i = threadIdx.x; i < FEATS_; i += blockDim.x) cs[i] = cond[n * FEATS_ + i];
    __syncthreads();
    int c = threadIdx.x;
    float sc = agb[c], sh = agb[C_ + c];
    const float4* w1 = (const float4*)(agw + (size_t)c * FEATS_);
    const float4* w2 = (const float4*)(agw + (size_t)(C_ + c) * FEATS_);
    const float4* cv = (const float4*)cs;
    for (int i = 0; i < FEATS_ / 4; i++) {
        float4 a = w1[i], b = w2[i], cc = cv[i];
        sc += a.x * cc.x + a.y * cc.y + a.z * cc.z + a.w * cc.w;
        sh += b.x * cc.x + b.y * cc.y + b.z * cc.z + b.w * cc.w;
    }
    float cnt = (float)(C_ * HW_);
    float mu  = stats[2 * n] / cnt;
    float var = stats[2 * n + 1] / cnt - mu * mu;
    float rstd = rsqrtf(var + EPS_);
    float al = rstd * (sc + 1.f);
    alpha[n * C_ + c] = al;
    beta[n * C_ + c]  = sh - mu * al;
}

// ---------------- effective q bias ----------------
__global__ __launch_bounds__(512) void qbias_kernel(const float* __restrict__ qw,
                                                    const float* __restrict__ qb,
                                                    const float* __restrict__ beta,
                                                    float* __restrict__ qbias) {
    int n = blockIdx.x;
    __shared__ float bs[C_];
    for (int i = threadIdx.x; i < C_; i += blockDim.x) bs[i] = beta[n * C_ + i];
    __syncthreads();
    int o = threadIdx.x;
    float acc = qb[o];
    const float4* w  = (const float4*)(qw + (size_t)o * C_);
    const float4* bv = (const float4*)bs;
    for (int i = 0; i < C_ / 4; i++) {
        float4 a = w[i], b = bv[i];
        acc += a.x * b.x + a.y * b.y + a.z * b.z + a.w * b.w;
    }
    qbias[n * C_ + o] = acc;
}

// ---------------- fp32 -> bf16 convert ----------------
__global__ __launch_bounds__(256) void cvt_kernel(const float* __restrict__ src,
                                                  u16* __restrict__ dst, int n4) {
    int i = blockIdx.x * 256 + threadIdx.x;
    if (i < n4) {
        float4 v = ((const float4*)src)[i];
        ushort4 w;
        w.x = f2bf(v.x); w.y = f2bf(v.y); w.z = f2bf(v.z); w.w = f2bf(v.w);
        ((ushort4*)dst)[i] = w;
    }
}

// ---------------- xT[n][hw][c] = input[n][c][hw] * alpha[n][c]  (bf16) ----------------
__global__ __launch_bounds__(256) void xt_kernel(const float* __restrict__ inp,
                                                 const float* __restrict__ alpha,
                                                 u16* __restrict__ xT) {
    int n = blockIdx.z, c0 = blockIdx.y * 64, h0 = blockIdx.x * 64;
    __shared__ float t[64][65];
    int tid = threadIdx.x;
    int rr = tid >> 4, cc = (tid & 15) * 4;
#pragma unroll
    for (int i = 0; i < 4; i++) {
        int cl = rr + i * 16;
        int c = c0 + cl;
        float4 v = *(const float4*)(inp + ((size_t)n * C_ + c) * HW_ + h0 + cc);
        float a = alpha[n * C_ + c];
        t[cl][cc + 0] = v.x * a; t[cl][cc + 1] = v.y * a;
        t[cl][cc + 2] = v.z * a; t[cl][cc + 3] = v.w * a;
    }
    __syncthreads();
#pragma unroll
    for (int i = 0; i < 4; i++) {
        int hl = rr + i * 16;
        ushort4 w;
        w.x = f2bf(t[cc + 0][hl]); w.y = f2bf(t[cc + 1][hl]);
        w.z = f2bf(t[cc + 2][hl]); w.w = f2bf(t[cc + 3][hl]);
        *(ushort4*)(xT + ((size_t)n * HW_ + h0 + hl) * C_ + c0 + cc) = w;
    }
}

// ---------------- layernorm(enc) -> e_b bf16 [token][768] ----------------
__global__ __launch_bounds__(256) void ln_kernel(const float* __restrict__ enc,
                                                 const float* __restrict__ lnw,
                                                 const float* __restrict__ lnb,
                                                 u16* __restrict__ eb) {
    int tok = blockIdx.x;
    const float* row = enc + (size_t)tok * CE_;
    int t = threadIdx.x;
    float v0 = row[t], v1 = row[t + 256], v2 = row[t + 512];
    float sum = v0 + v1 + v2;
    float sq  = v0 * v0 + v1 * v1 + v2 * v2;
    for (int off = 32; off; off >>= 1) {
        sum += __shfl_down(sum, off);
        sq  += __shfl_down(sq, off);
    }
    __shared__ float red[8];
    int wid = t >> 6, lane = t & 63;
    if (lane == 0) { red[wid] = sum; red[4 + wid] = sq; }
    __syncthreads();
    float tot = red[0] + red[1] + red[2] + red[3];
    float tsq = red[4] + red[5] + red[6] + red[7];
    float mu  = tot / CE_;
    float var = tsq / CE_ - mu * mu;
    float rstd = rsqrtf(var + EPS_);
    u16* o = eb + (size_t)tok * CE_;
    o[t]       = f2bf((v0 - mu) * rstd * lnw[t] + lnb[t]);
    o[t + 256] = f2bf((v1 - mu) * rstd * lnw[t + 256] + lnb[t + 256]);
    o[t + 512] = f2bf((v2 - mu) * rstd * lnw[t + 512] + lnb[t + 512]);
}

// ---------------- MFMA GEMM mainloop: C[m][nn] = sum_k A[m][k]*B[nn][k] ----------------
// 128x128 tile, BK=64, 4 waves (2x2 of 64x64), XOR-swizzled LDS (pre-swizzled global src).
__device__ __forceinline__ void gemm_mainloop(const u16* __restrict__ A, int lda, int arow0,
                                              const u16* __restrict__ B, int ldb, int brow0, int brmax,
                                              int K, f32x4 (&acc)[4][4], u16* As, u16* Bs) {
    int tid = threadIdx.x;
    int lane = tid & 63;
    int wm = ((tid >> 6) >> 1) * 64, wn = ((tid >> 6) & 1) * 64;
    int srow = tid >> 3;                 // 0..31 (+ i*32)
    int sw = (tid & 7) ^ (srow & 7);     // swizzled 16B source slot
    int ldsoff = tid * 8;                // u16 units = 16 B / thread
    for (int kt = 0; kt < K; kt += 64) {
        __syncthreads();
#pragma unroll
        for (int i = 0; i < 4; i++) {
            int ar = arow0 + i * 32 + srow;
            const u16* ga = A + (size_t)ar * lda + kt + sw * 8;
            __builtin_amdgcn_global_load_lds((AS1 void*)ga, (AS3 void*)(As + i * 2048 + ldsoff), 16, 0, 0);
            int br = brow0 + i * 32 + srow; if (br > brmax) br = brmax;
            const u16* gb = B + (size_t)br * ldb + kt + sw * 8;
            __builtin_amdgcn_global_load_lds((AS1 void*)gb, (AS3 void*)(Bs + i * 2048 + ldsoff), 16, 0, 0);
        }
        __syncthreads();
#pragma unroll
        for (int kk = 0; kk < 2; kk++) {
            bf16x8 af[4], bfv[4];
            int ks = kk * 4 + (lane >> 4);
#pragma unroll
            for (int mi = 0; mi < 4; mi++) {
                int r = wm + mi * 16 + (lane & 15);
                af[mi] = *(const bf16x8*)(As + r * 64 + (ks ^ (r & 7)) * 8);
            }
#pragma unroll
            for (int ni = 0; ni < 4; ni++) {
                int r = wn + ni * 16 + (lane & 15);
                bfv[ni] = *(const bf16x8*)(Bs + r * 64 + (ks ^ (r & 7)) * 8);
            }
#pragma unroll
            for (int mi = 0; mi < 4; mi++)
#pragma unroll
                for (int ni = 0; ni < 4; ni++)
                    acc[mi][ni] = __builtin_amdgcn_mfma_f32_16x16x32_bf16(af[mi], bfv[ni], acc[mi][ni], 0, 0, 0);
        }
    }
}

// ---------------- Q GEMM: CT = q_t[n][hw][o] bf16, bias qbias[n][o] ----------------
__global__ __launch_bounds__(256) void gemm_q_mfma(const u16* __restrict__ qwb,
                                                   const u16* __restrict__ xT,
                                                   const float* __restrict__ qbias,
                                                   u16* __restrict__ qt) {
    __shared__ __align__(16) u16 As[128 * 64];
    __shared__ __align__(16) u16 Bs[128 * 64];
    int n = blockIdx.z;
    int arow0 = blockIdx.y * 128, brow0 = blockIdx.x * 128;
    f32x4 acc[4][4];
#pragma unroll
    for (int mi = 0; mi < 4; mi++)
#pragma unroll
        for (int ni = 0; ni < 4; ni++) acc[mi][ni] = 0.f;
    gemm_mainloop(qwb, C_, arow0, xT + (size_t)n * HW_ * C_, C_, brow0, HW_ - 1, C_, acc, As, Bs);
    int lane = threadIdx.x & 63, wid = threadIdx.x >> 6;
    int wm = (wid >> 1) * 64, wn = (wid & 1) * 64;
    u16* CT = qt + (size_t)n * HW_ * C_;
    const float* qb = qbias + n * C_;
#pragma unroll
    for (int mi = 0; mi < 4; mi++) {
        int row = arow0 + wm + mi * 16 + ((lane >> 4) << 2);
        float4 b4 = *(const float4*)(qb + row);
#pragma unroll
        for (int ni = 0; ni < 4; ni++) {
            int col = brow0 + wn + ni * 16 + (lane & 15);
            f32x4 v = acc[mi][ni];
            ushort4 w;
            w.x = f2bf(v.x + b4.x); w.y = f2bf(v.y + b4.y);
            w.z = f2bf(v.z + b4.z); w.w = f2bf(v.w + b4.w);
            *(ushort4*)(CT + (size_t)col * C_ + row) = w;
        }
    }
}

// ---------------- KV GEMM: CT = kv_b[token][j] bf16, bias kvb[j], guard token<1232 ----------------
__global__ __launch_bounds__(256) void gemm_kv_mfma(const u16* __restrict__ kvwb,
                                                    const u16* __restrict__ eb,
                                                    const float* __restrict__ kvbias,
                                                    u16* __restrict__ kvo) {
    __shared__ __align__(16) u16 As[128 * 64];
    __shared__ __align__(16) u16 Bs[128 * 64];
    int arow0 = blockIdx.y * 128, brow0 = blockIdx.x * 128;
    f32x4 acc[4][4];
#pragma unroll
    for (int mi = 0; mi < 4; mi++)
#pragma unroll
        for (int ni = 0; ni < 4; ni++) acc[mi][ni] = 0.f;
    gemm_mainloop(kvwb, CE_, arow0, eb, CE_, brow0, TOK_ - 1, CE_, acc, As, Bs);
    int lane = threadIdx.x & 63, wid = threadIdx.x >> 6;
    int wm = (wid >> 1) * 64, wn = (wid & 1) * 64;
#pragma unroll
    for (int mi = 0; mi < 4; mi++) {
        int row = arow0 + wm + mi * 16 + ((lane >> 4) << 2);
        float4 b4 = *(const float4*)(kvbias + row);
#pragma unroll
        for (int ni = 0; ni < 4; ni++) {
            int col = brow0 + wn + ni * 16 + (lane & 15);
            if (col < TOK_) {
                f32x4 v = acc[mi][ni];
                ushort4 w;
                w.x = f2bf(v.x + b4.x); w.y = f2bf(v.y + b4.y);
                w.z = f2bf(v.z + b4.z); w.w = f2bf(v.w + b4.w);
                *(ushort4*)(kvo + (size_t)col * 1024 + row) = w;
            }
        }
    }
}

// ---------------- OUT GEMM: out[n][o][hw] = acc + ob[o] + input, fp32 ----------------
__global__ __launch_bounds__(256) void gemm_out_mfma(const u16* __restrict__ owb,
                                                     const u16* __restrict__ yT,
                                                     const float* __restrict__ ob,
                                                     const float* __restrict__ inp,
                                                     float* __restrict__ outp) {
    __shared__ __align__(16) u16 As[128 * 64];
    __shared__ __align__(16) u16 Bs[128 * 64];
    int n = blockIdx.z;
    int arow0 = blockIdx.y * 128, brow0 = blockIdx.x * 128;
    f32x4 acc[4][4];
#pragma unroll
    for (int mi = 0; mi < 4; mi++)
#pragma unroll
        for (int ni = 0; ni < 4; ni++) acc[mi][ni] = 0.f;
    gemm_mainloop(owb, C_, arow0, yT + (size_t)n * HW_ * C_, C_, brow0, HW_ - 1, C_, acc, As, Bs);
    int lane = threadIdx.x & 63, wid = threadIdx.x >> 6;
    int wm = (wid >> 1) * 64, wn = (wid & 1) * 64;
    float* Co = outp + (size_t)n * C_ * HW_;
    const float* In = inp + (size_t)n * C_ * HW_;
#pragma unroll
    for (int mi = 0; mi < 4; mi++) {
        int row = arow0 + wm + mi * 16 + ((lane >> 4) << 2);
        float4 b4 = *(const float4*)(ob + row);
#pragma unroll
        for (int ni = 0; ni < 4; ni++) {
            int col = brow0 + wn + ni * 16 + (lane & 15);
            f32x4 v = acc[mi][ni];
            size_t i0 = (size_t)row * HW_ + col;
            Co[i0]            = v.x + b4.x + In[i0];
            Co[i0 + HW_]      = v.y + b4.y + In[i0 + HW_];
            Co[i0 + 2 * HW_]  = v.z + b4.z + In[i0 + 2 * HW_];
            Co[i0 + 3 * HW_]  = v.w + b4.w + In[i0 + 3 * HW_];
        }
    }
}

// ---------------- attention: q_t bf16 -> y_t bf16, fp32 flash math ----------------
__global__ __launch_bounds__(256) void attn_kernel(const u16* __restrict__ kvb,
                                                   const float* __restrict__ mask,
                                                   const u16* __restrict__ qt,
                                                   u16* __restrict__ yt) {
    int nh = blockIdx.x;
    int n = nh >> 3, h = nh & 7;
    int qpos = blockIdx.y * 256 + threadIdx.x;
    __shared__ float kl[S_ * D_];
    __shared__ float vl[S_ * D_];
    __shared__ float msk[S_ + 3];
    for (int i = threadIdx.x; i < S_ * D_; i += 256) {
        int s = i >> 6, d = i & 63;
        const u16* row = kvb + ((size_t)(n * S_ + s)) * 1024 + h * 64 + d;
        kl[i] = bf2f(row[0]);
        vl[i] = bf2f(row[512]);
    }
    for (int i = threadIdx.x; i < S_; i += 256) msk[i] = mask[n * S_ + i] * 10000.f;
    __syncthreads();

    const uint4* qr = (const uint4*)(qt + ((size_t)(n * HW_) + qpos) * C_ + h * 64);
    float q[64];
#pragma unroll
    for (int i = 0; i < 8; i++) {           // 8 x uint4 = 64 bf16
        uint4 u = qr[i];
        q[i * 8 + 0] = __uint_as_float(u.x << 16); q[i * 8 + 1] = __uint_as_float(u.x & 0xffff0000u);
        q[i * 8 + 2] = __uint_as_float(u.y << 16); q[i * 8 + 3] = __uint_as_float(u.y & 0xffff0000u);
        q[i * 8 + 4] = __uint_as_float(u.z << 16); q[i * 8 + 5] = __uint_as_float(u.z & 0xffff0000u);
        q[i * 8 + 6] = __uint_as_float(u.w << 16); q[i * 8 + 7] = __uint_as_float(u.w & 0xffff0000u);
    }
    float m = -1e30f, l = 0.f;
    float ya[64];
#pragma unroll
    for (int d = 0; d < 64; d++) ya[d] = 0.f;
    for (int j = 0; j < S_; j++) {
        const float* kr = &kl[j * 64];
        float dot = 0.f;
#pragma unroll
        for (int d = 0; d < 64; d++) dot = fmaf(q[d], kr[d], dot);
        float sc = dot * 0.125f - msk[j];
        if (sc > m) {
            float corr = __expf(m - sc);
            l *= corr;
#pragma unroll
            for (int d = 0; d < 64; d++) ya[d] *= corr;
            m = sc;
        }
        float p = __expf(sc - m);
        l += p;
        const float* vr = &vl[j * 64];
#pragma unroll
        for (int d = 0; d < 64; d++) ya[d] = fmaf(p, vr[d], ya[d]);
    }
    float inv = 1.f / l;
    uint4* yw = (uint4*)(yt + ((size_t)(n * HW_) + qpos) * C_ + h * 64);
#pragma unroll
    for (int i = 0; i < 8; i++) {           // 8 x uint4 = 64 bf16
        uint4 u;
        u.x = (unsigned)f2bf(ya[i * 8 + 0] * inv) | ((unsigned)f2bf(ya[i * 8 + 1] * inv) << 16);
        u.y = (unsigned)f2bf(ya[i * 8 + 2] * inv) | ((unsigned)f2bf(ya[i * 8 + 3] * inv) << 16);
        u.z = (unsigned)f2bf(ya[i * 8 + 4] * inv) | ((unsigned)f2bf(ya[i * 8 + 5] * inv) << 16);
        u.w = (unsigned)f2bf(ya[i * 8 + 6] * inv) | ((unsigned)f2bf(ya[i * 8 + 7] * inv) << 16);
        yw[i] = u;
    }
}

extern "C" void kernel_launch(void* const* d_in, const int* in_sizes, int n_in,
                              void* d_out, int out_size, void* d_ws, size_t ws_size,
                              hipStream_t stream) {
    const float* inp  = (const float*)d_in[0];
    const float* cond = (const float*)d_in[1];
    const float* enc  = (const float*)d_in[2];
    const float* mask = (const float*)d_in[3];
    const float* agw  = (const float*)d_in[4];
    const float* agb  = (const float*)d_in[5];
    const float* lnw  = (const float*)d_in[6];
    const float* lnb  = (const float*)d_in[7];
    const float* qw   = (const float*)d_in[8];
    const float* qb   = (const float*)d_in[9];
    const float* kvw  = (const float*)d_in[10];
    const float* kvb  = (const float*)d_in[11];
    const float* ow   = (const float*)d_in[12];
    const float* ob   = (const float*)d_in[13];
    float* ws  = (float*)d_ws;
    float* out = (float*)d_out;
    u16* wsu = (u16*)((char*)d_ws + WSU_BYTE);

    hipMemsetAsync(ws + WS_STATS, 0, 32 * sizeof(float), stream);
    stats_kernel<<<dim3(N_ * 16), 256, 0, stream>>>(inp, ws + WS_STATS);
    alphabeta_kernel<<<N_, 512, 0, stream>>>(cond, agw, agb, ws + WS_STATS,
                                             ws + WS_ALPHA, ws + WS_BETA);
    qbias_kernel<<<N_, 512, 0, stream>>>(qw, qb, ws + WS_BETA, ws + WS_QBIAS);

    cvt_kernel<<<dim3(C_ * C_ / 1024), 256, 0, stream>>>(qw, wsu + U_QW, C_ * C_ / 4);
    cvt_kernel<<<dim3(C_ * C_ / 1024), 256, 0, stream>>>(ow, wsu + U_OW, C_ * C_ / 4);
    cvt_kernel<<<dim3(1024 * CE_ / 1024), 256, 0, stream>>>(kvw, wsu + U_KVW, 1024 * CE_ / 4);

    xt_kernel<<<dim3(HW_ / 64, C_ / 64, N_), 256, 0, stream>>>(inp, ws + WS_ALPHA, wsu + U_XT);
    ln_kernel<<<dim3(TOK_), 256, 0, stream>>>(enc, lnw, lnb, wsu + U_EB);

    gemm_kv_mfma<<<dim3((TOK_ + 127) / 128, 1024 / 128), 256, 0, stream>>>(
        wsu + U_KVW, wsu + U_EB, kvb, wsu + U_KVB);
    gemm_q_mfma<<<dim3(HW_ / 128, C_ / 128, N_), 256, 0, stream>>>(
        wsu + U_QW, wsu + U_XT, ws + WS_QBIAS, wsu + U_QT);

    attn_kernel<<<dim3(N_ * NH_, HW_ / 256), 256, 0, stream>>>(
        wsu + U_KVB, mask, wsu + U_QT, wsu + U_XT);   // yT aliases xT (consumed)

    gemm_out_mfma<<<dim3(HW_ / 128, C_ / 128, N_), 256, 0, stream>>>(
        wsu + U_OW, wsu + U_XT, ob, inp, out);
}

// Round 4
// 218.554 us; speedup vs baseline: 4.0971x; 1.2059x over previous
//
#include <hip/hip_runtime.h>
#include <math.h>

typedef unsigned short u16;
typedef __bf16 bf16x8 __attribute__((ext_vector_type(8)));
typedef float f32x4 __attribute__((ext_vector_type(4)));

#define AS1 __attribute__((address_space(1)))
#define AS3 __attribute__((address_space(3)))

#define N_    16
#define C_    512
#define HW_   1024
#define CE_   768
#define S_    77
#define NH_   8
#define D_    64
#define FEATS_ 512
#define EPS_  1e-5f
#define TOK_  (N_ * S_)   // 1232

// fp32 workspace (float offsets)
#define WS_STATS 0
#define WS_ALPHA 1024
#define WS_BETA  (WS_ALPHA + 8192)
#define WS_QBIAS (WS_BETA + 8192)
// u16 (bf16) workspace, base at byte 131072
#define WSU_BYTE 131072
#define U_QW  0
#define U_OW  262144
#define U_KVW 524288
#define U_EB  1310720              // 1232*768   = 946176
#define U_KVB 2256896              // 1232*1024  = 1261568
#define U_QT  3518464              // 16*1024*512= 8388608
#define U_XT  11907072             // xT, later reused as yT (attn writes after gemm_q consumed xT)

__device__ __forceinline__ u16 f2bf(float f) {
    unsigned u = __float_as_uint(f);
    return (u16)((u + 0x7FFFu + ((u >> 16) & 1u)) >> 16);
}
__device__ __forceinline__ float bf2f(u16 h) {
    return __uint_as_float(((unsigned)h) << 16);
}

// ---------------- per-sample mean/var partial sums ----------------
__global__ __launch_bounds__(256) void stats_kernel(const float* __restrict__ inp,
                                                    float* __restrict__ stats) {
    int n = blockIdx.x >> 4;
    int slice = blockIdx.x & 15;
    const float* base = inp + (size_t)n * C_ * HW_ + slice * (C_ * HW_ / 16);
    float s = 0.f, s2 = 0.f;
    const float4* b4 = (const float4*)base;
    for (int i = threadIdx.x; i < (C_ * HW_ / 16) / 4; i += 256) {
        float4 v = b4[i];
        s  += v.x + v.y + v.z + v.w;
        s2 += v.x * v.x + v.y * v.y + v.z * v.z + v.w * v.w;
    }
    for (int off = 32; off; off >>= 1) {
        s  += __shfl_down(s, off);
        s2 += __shfl_down(s2, off);
    }
    __shared__ float sh[8];
    int wid = threadIdx.x >> 6, lane = threadIdx.x & 63;
    if (lane == 0) { sh[wid] = s; sh[4 + wid] = s2; }
    __syncthreads();
    if (threadIdx.x == 0) {
        atomicAdd(&stats[2 * n], sh[0] + sh[1] + sh[2] + sh[3]);
        atomicAdd(&stats[2 * n + 1], sh[4] + sh[5] + sh[6] + sh[7]);
    }
}

// ---------------- fold instance-norm + AdaGN -> alpha, beta ----------------
__global__ __launch_bounds__(512) void alphabeta_kernel(const float* __restrict__ cond,
                                                        const float* __restrict__ agw,
                                                        const float* __restrict__ agb,
                                                        const float* __restrict__ stats,
                                                        float* __restrict__ alpha,
                                                        float* __restrict__ beta) {
    int n = blockIdx.x;
    __shared__ float cs[FEATS_];
    for (int i = threadIdx.x; i < FEATS_; i += blockDim.x) cs[i] = cond[n * FEATS_ + i];
    __syncthreads();
    int c = threadIdx.x;
    float sc = agb[c], sh = agb[C_ + c];
    const float4* w1 = (const float4*)(agw + (size_t)c * FEATS_);
    const float4* w2 = (const float4*)(agw + (size_t)(C_ + c) * FEATS_);
    const float4* cv = (const float4*)cs;
    for (int i = 0; i < FEATS_ / 4; i++) {
        float4 a = w1[i], b = w2[i], cc = cv[i];
        sc += a.x * cc.x + a.y * cc.y + a.z * cc.z + a.w * cc.w;
        sh += b.x * cc.x + b.y * cc.y + b.z * cc.z + b.w * cc.w;
    }
    float cnt = (float)(C_ * HW_);
    float mu  = stats[2 * n] / cnt;
    float var = stats[2 * n + 1] / cnt - mu * mu;
    float rstd = rsqrtf(var + EPS_);
    float al = rstd * (sc + 1.f);
    alpha[n * C_ + c] = al;
    beta[n * C_ + c]  = sh - mu * al;
}

// ---------------- effective q bias ----------------
__global__ __launch_bounds__(512) void qbias_kernel(const float* __restrict__ qw,
                                                    const float* __restrict__ qb,
                                                    const float* __restrict__ beta,
                                                    float* __restrict__ qbias) {
    int n = blockIdx.x;
    __shared__ float bs[C_];
    for (int i = threadIdx.x; i < C_; i += blockDim.x) bs[i] = beta[n * C_ + i];
    __syncthreads();
    int o = threadIdx.x;
    float acc = qb[o];
    const float4* w  = (const float4*)(qw + (size_t)o * C_);
    const float4* bv = (const float4*)bs;
    for (int i = 0; i < C_ / 4; i++) {
        float4 a = w[i], b = bv[i];
        acc += a.x * b.x + a.y * b.y + a.z * b.z + a.w * b.w;
    }
    qbias[n * C_ + o] = acc;
}

// ---------------- fp32 -> bf16 convert ----------------
__global__ __launch_bounds__(256) void cvt_kernel(const float* __restrict__ src,
                                                  u16* __restrict__ dst, int n4) {
    int i = blockIdx.x * 256 + threadIdx.x;
    if (i < n4) {
        float4 v = ((const float4*)src)[i];
        ushort4 w;
        w.x = f2bf(v.x); w.y = f2bf(v.y); w.z = f2bf(v.z); w.w = f2bf(v.w);
        ((ushort4*)dst)[i] = w;
    }
}

// ---------------- xT[n][hw][c] = input[n][c][hw] * alpha[n][c]  (bf16) ----------------
__global__ __launch_bounds__(256) void xt_kernel(const float* __restrict__ inp,
                                                 const float* __restrict__ alpha,
                                                 u16* __restrict__ xT) {
    int n = blockIdx.z, c0 = blockIdx.y * 64, h0 = blockIdx.x * 64;
    __shared__ float t[64][65];
    int tid = threadIdx.x;
    int rr = tid >> 4, cc = (tid & 15) * 4;
#pragma unroll
    for (int i = 0; i < 4; i++) {
        int cl = rr + i * 16;
        int c = c0 + cl;
        float4 v = *(const float4*)(inp + ((size_t)n * C_ + c) * HW_ + h0 + cc);
        float a = alpha[n * C_ + c];
        t[cl][cc + 0] = v.x * a; t[cl][cc + 1] = v.y * a;
        t[cl][cc + 2] = v.z * a; t[cl][cc + 3] = v.w * a;
    }
    __syncthreads();
#pragma unroll
    for (int i = 0; i < 4; i++) {
        int hl = rr + i * 16;
        ushort4 w;
        w.x = f2bf(t[cc + 0][hl]); w.y = f2bf(t[cc + 1][hl]);
        w.z = f2bf(t[cc + 2][hl]); w.w = f2bf(t[cc + 3][hl]);
        *(ushort4*)(xT + ((size_t)n * HW_ + h0 + hl) * C_ + c0 + cc) = w;
    }
}

// ---------------- layernorm(enc) -> e_b bf16 [token][768] ----------------
__global__ __launch_bounds__(256) void ln_kernel(const float* __restrict__ enc,
                                                 const float* __restrict__ lnw,
                                                 const float* __restrict__ lnb,
                                                 u16* __restrict__ eb) {
    int tok = blockIdx.x;
    const float* row = enc + (size_t)tok * CE_;
    int t = threadIdx.x;
    float v0 = row[t], v1 = row[t + 256], v2 = row[t + 512];
    float sum = v0 + v1 + v2;
    float sq  = v0 * v0 + v1 * v1 + v2 * v2;
    for (int off = 32; off; off >>= 1) {
        sum += __shfl_down(sum, off);
        sq  += __shfl_down(sq, off);
    }
    __shared__ float red[8];
    int wid = t >> 6, lane = t & 63;
    if (lane == 0) { red[wid] = sum; red[4 + wid] = sq; }
    __syncthreads();
    float tot = red[0] + red[1] + red[2] + red[3];
    float tsq = red[4] + red[5] + red[6] + red[7];
    float mu  = tot / CE_;
    float var = tsq / CE_ - mu * mu;
    float rstd = rsqrtf(var + EPS_);
    u16* o = eb + (size_t)tok * CE_;
    o[t]       = f2bf((v0 - mu) * rstd * lnw[t] + lnb[t]);
    o[t + 256] = f2bf((v1 - mu) * rstd * lnw[t + 256] + lnb[t + 256]);
    o[t + 512] = f2bf((v2 - mu) * rstd * lnw[t + 512] + lnb[t + 512]);
}

// ---------------- MFMA GEMM mainloop: C[m][nn] = sum_k A[m][k]*B[nn][k] ----------------
__device__ __forceinline__ void gemm_mainloop(const u16* __restrict__ A, int lda, int arow0,
                                              const u16* __restrict__ B, int ldb, int brow0, int brmax,
                                              int K, f32x4 (&acc)[4][4], u16* As, u16* Bs) {
    int tid = threadIdx.x;
    int lane = tid & 63;
    int wm = ((tid >> 6) >> 1) * 64, wn = ((tid >> 6) & 1) * 64;
    int srow = tid >> 3;                 // 0..31 (+ i*32)
    int sw = (tid & 7) ^ (srow & 7);     // swizzled 16B source slot
    int ldsoff = tid * 8;                // u16 units = 16 B / thread
    for (int kt = 0; kt < K; kt += 64) {
        __syncthreads();
#pragma unroll
        for (int i = 0; i < 4; i++) {
            int ar = arow0 + i * 32 + srow;
            const u16* ga = A + (size_t)ar * lda + kt + sw * 8;
            __builtin_amdgcn_global_load_lds((AS1 void*)ga, (AS3 void*)(As + i * 2048 + ldsoff), 16, 0, 0);
            int br = brow0 + i * 32 + srow; if (br > brmax) br = brmax;
            const u16* gb = B + (size_t)br * ldb + kt + sw * 8;
            __builtin_amdgcn_global_load_lds((AS1 void*)gb, (AS3 void*)(Bs + i * 2048 + ldsoff), 16, 0, 0);
        }
        __syncthreads();
#pragma unroll
        for (int kk = 0; kk < 2; kk++) {
            bf16x8 af[4], bfv[4];
            int ks = kk * 4 + (lane >> 4);
#pragma unroll
            for (int mi = 0; mi < 4; mi++) {
                int r = wm + mi * 16 + (lane & 15);
                af[mi] = *(const bf16x8*)(As + r * 64 + (ks ^ (r & 7)) * 8);
            }
#pragma unroll
            for (int ni = 0; ni < 4; ni++) {
                int r = wn + ni * 16 + (lane & 15);
                bfv[ni] = *(const bf16x8*)(Bs + r * 64 + (ks ^ (r & 7)) * 8);
            }
#pragma unroll
            for (int mi = 0; mi < 4; mi++)
#pragma unroll
                for (int ni = 0; ni < 4; ni++)
                    acc[mi][ni] = __builtin_amdgcn_mfma_f32_16x16x32_bf16(af[mi], bfv[ni], acc[mi][ni], 0, 0, 0);
        }
    }
}

// ---------------- Q GEMM: CT = q_t[n][hw][o] bf16, bias qbias[n][o] ----------------
__global__ __launch_bounds__(256) void gemm_q_mfma(const u16* __restrict__ qwb,
                                                   const u16* __restrict__ xT,
                                                   const float* __restrict__ qbias,
                                                   u16* __restrict__ qt) {
    __shared__ __align__(16) u16 As[128 * 64];
    __shared__ __align__(16) u16 Bs[128 * 64];
    int n = blockIdx.z;
    int arow0 = blockIdx.y * 128, brow0 = blockIdx.x * 128;
    f32x4 acc[4][4];
#pragma unroll
    for (int mi = 0; mi < 4; mi++)
#pragma unroll
        for (int ni = 0; ni < 4; ni++) acc[mi][ni] = 0.f;
    gemm_mainloop(qwb, C_, arow0, xT + (size_t)n * HW_ * C_, C_, brow0, HW_ - 1, C_, acc, As, Bs);
    int lane = threadIdx.x & 63, wid = threadIdx.x >> 6;
    int wm = (wid >> 1) * 64, wn = (wid & 1) * 64;
    u16* CT = qt + (size_t)n * HW_ * C_;
    const float* qb = qbias + n * C_;
#pragma unroll
    for (int mi = 0; mi < 4; mi++) {
        int row = arow0 + wm + mi * 16 + ((lane >> 4) << 2);
        float4 b4 = *(const float4*)(qb + row);
#pragma unroll
        for (int ni = 0; ni < 4; ni++) {
            int col = brow0 + wn + ni * 16 + (lane & 15);
            f32x4 v = acc[mi][ni];
            ushort4 w;
            w.x = f2bf(v.x + b4.x); w.y = f2bf(v.y + b4.y);
            w.z = f2bf(v.z + b4.z); w.w = f2bf(v.w + b4.w);
            *(ushort4*)(CT + (size_t)col * C_ + row) = w;
        }
    }
}

// ---------------- KV GEMM: CT = kv_b[token][j] bf16, bias kvb[j], guard token<1232 ----------------
__global__ __launch_bounds__(256) void gemm_kv_mfma(const u16* __restrict__ kvwb,
                                                    const u16* __restrict__ eb,
                                                    const float* __restrict__ kvbias,
                                                    u16* __restrict__ kvo) {
    __shared__ __align__(16) u16 As[128 * 64];
    __shared__ __align__(16) u16 Bs[128 * 64];
    int arow0 = blockIdx.y * 128, brow0 = blockIdx.x * 128;
    f32x4 acc[4][4];
#pragma unroll
    for (int mi = 0; mi < 4; mi++)
#pragma unroll
        for (int ni = 0; ni < 4; ni++) acc[mi][ni] = 0.f;
    gemm_mainloop(kvwb, CE_, arow0, eb, CE_, brow0, TOK_ - 1, CE_, acc, As, Bs);
    int lane = threadIdx.x & 63, wid = threadIdx.x >> 6;
    int wm = (wid >> 1) * 64, wn = (wid & 1) * 64;
#pragma unroll
    for (int mi = 0; mi < 4; mi++) {
        int row = arow0 + wm + mi * 16 + ((lane >> 4) << 2);
        float4 b4 = *(const float4*)(kvbias + row);
#pragma unroll
        for (int ni = 0; ni < 4; ni++) {
            int col = brow0 + wn + ni * 16 + (lane & 15);
            if (col < TOK_) {
                f32x4 v = acc[mi][ni];
                ushort4 w;
                w.x = f2bf(v.x + b4.x); w.y = f2bf(v.y + b4.y);
                w.z = f2bf(v.z + b4.z); w.w = f2bf(v.w + b4.w);
                *(ushort4*)(kvo + (size_t)col * 1024 + row) = w;
            }
        }
    }
}

// ---------------- OUT GEMM: out[n][o][hw] = acc + ob[o] + input, fp32 ----------------
__global__ __launch_bounds__(256) void gemm_out_mfma(const u16* __restrict__ owb,
                                                     const u16* __restrict__ yT,
                                                     const float* __restrict__ ob,
                                                     const float* __restrict__ inp,
                                                     float* __restrict__ outp) {
    __shared__ __align__(16) u16 As[128 * 64];
    __shared__ __align__(16) u16 Bs[128 * 64];
    int n = blockIdx.z;
    int arow0 = blockIdx.y * 128, brow0 = blockIdx.x * 128;
    f32x4 acc[4][4];
#pragma unroll
    for (int mi = 0; mi < 4; mi++)
#pragma unroll
        for (int ni = 0; ni < 4; ni++) acc[mi][ni] = 0.f;
    gemm_mainloop(owb, C_, arow0, yT + (size_t)n * HW_ * C_, C_, brow0, HW_ - 1, C_, acc, As, Bs);
    int lane = threadIdx.x & 63, wid = threadIdx.x >> 6;
    int wm = (wid >> 1) * 64, wn = (wid & 1) * 64;
    float* Co = outp + (size_t)n * C_ * HW_;
    const float* In = inp + (size_t)n * C_ * HW_;
#pragma unroll
    for (int mi = 0; mi < 4; mi++) {
        int row = arow0 + wm + mi * 16 + ((lane >> 4) << 2);
        float4 b4 = *(const float4*)(ob + row);
#pragma unroll
        for (int ni = 0; ni < 4; ni++) {
            int col = brow0 + wn + ni * 16 + (lane & 15);
            f32x4 v = acc[mi][ni];
            size_t i0 = (size_t)row * HW_ + col;
            Co[i0]            = v.x + b4.x + In[i0];
            Co[i0 + HW_]      = v.y + b4.y + In[i0 + HW_];
            Co[i0 + 2 * HW_]  = v.z + b4.z + In[i0 + 2 * HW_];
            Co[i0 + 3 * HW_]  = v.w + b4.w + In[i0 + 3 * HW_];
        }
    }
}

// ---------------- MFMA attention (swapped-operand): 64 q-rows / block, 4 waves ----------------
// S^T = mfma(K,Q) so each lane's column = its own q-row; softmax in-register;
// P (bf16, 1/l folded) -> LDS; Y^T = mfma(V^T, P).
__global__ __launch_bounds__(256) void attn_mfma(const u16* __restrict__ kvb,
                                                 const float* __restrict__ mask,
                                                 const u16* __restrict__ qt,
                                                 u16* __restrict__ yt) {
    int nh = blockIdx.x;                  // n*8 + h
    int n = nh >> 3, h = nh & 7;
    int qb = blockIdx.y;                  // 0..15, 64 q-rows each
    __shared__ __align__(16) u16 Qs[64 * 64];     //  8 KB, swizzled
    __shared__ __align__(16) u16 Ks[80 * 64];     // 10 KB, swizzled (rows>=77 clamped)
    __shared__ __align__(16) u16 VT[64 * 104];    // 13 KB, VT[d][key], keys>=77 zeroed
    __shared__ __align__(16) u16 Ps[64 * 104];    // 13 KB, P[qrow][key], keys 80..95 zeroed
    __shared__ float msk[80];
    int tid = threadIdx.x;
    int lane = tid & 63, w = tid >> 6;
    int g = lane >> 4, l15 = lane & 15;

    // stage Q (64x64) via global_load_lds, pre-swizzled source
    const u16* qbase = qt + ((size_t)(n * HW_ + qb * 64)) * C_ + h * 64;
#pragma unroll
    for (int pass = 0; pass < 2; pass++) {
        int idx = pass * 256 + tid;
        int row = idx >> 3, slot = idx & 7;
        int sw = slot ^ (row & 7);
        __builtin_amdgcn_global_load_lds((AS1 void*)(qbase + (size_t)row * C_ + sw * 8),
                                         (AS3 void*)(Qs + idx * 8), 16, 0, 0);
    }
    // stage K (80 rows; rows >=77 clamp to 76, their p forced 0 later)
    const u16* kbase = kvb + (size_t)(n * S_) * 1024 + h * 64;
#pragma unroll
    for (int pass = 0; pass < 3; pass++) {
        int idx = pass * 256 + tid;
        if (idx < 640) {
            int row = idx >> 3, slot = idx & 7;
            int srow = row < S_ ? row : S_ - 1;
            int sw = slot ^ (row & 7);
            __builtin_amdgcn_global_load_lds((AS1 void*)(kbase + (size_t)srow * 1024 + sw * 8),
                                             (AS3 void*)(Ks + idx * 8), 16, 0, 0);
        }
    }
    // stage V^T[d][key], zero keys >= 77 (prevents NaN*0 in PV pad region)
    {
        int d = tid & 63, sg = tid >> 6;
        const u16* vbase = kvb + (size_t)(n * S_) * 1024 + 512 + h * 64 + d;
        for (int s = sg; s < 104; s += 4) {
            u16 v = (s < S_) ? vbase[(size_t)s * 1024] : (u16)0;
            VT[d * 104 + s] = v;
        }
    }
    // zero P cols 80..95 (keys 80..95 feed the kk=2 PV step)
    for (int i = tid; i < 512; i += 256) {
        int r = i >> 3, cp = i & 7;
        *(unsigned*)&Ps[r * 104 + 80 + cp * 2] = 0u;
    }
    if (tid < 80) msk[tid] = (tid < S_) ? mask[n * S_ + tid] * 10000.f : 0.f;
    __syncthreads();

    int qrow = w * 16 + l15;             // this lane's q-row (local 0..63)

    // Q B-fragments (reused across all key blocks)
    bf16x8 qf[2];
#pragma unroll
    for (int kk = 0; kk < 2; kk++) {
        int s8 = kk * 4 + g;
        qf[kk] = *(const bf16x8*)(Qs + qrow * 64 + (s8 ^ (qrow & 7)) * 8);
    }
    // S^T = K · Q^T   (5 key-blocks of 16)
    f32x4 sc[5];
#pragma unroll
    for (int kb = 0; kb < 5; kb++) {
        sc[kb] = 0.f;
#pragma unroll
        for (int kk = 0; kk < 2; kk++) {
            int r = kb * 16 + l15;
            int s8 = kk * 4 + g;
            bf16x8 kf = *(const bf16x8*)(Ks + r * 64 + (s8 ^ (r & 7)) * 8);
            sc[kb] = __builtin_amdgcn_mfma_f32_16x16x32_bf16(kf, qf[kk], sc[kb], 0, 0, 0);
        }
    }
    // softmax over keys for this lane's q-row (values spread: 5 kb x 4 regs, +xor16/32)
    float sv[5][4];
    float mx = -3e38f;
#pragma unroll
    for (int kb = 0; kb < 5; kb++)
#pragma unroll
        for (int j = 0; j < 4; j++) {
            int key = kb * 16 + g * 4 + j;
            float s = sc[kb][j] * 0.125f - msk[key];
            sv[kb][j] = s;
            if (key < S_) mx = fmaxf(mx, s);
        }
    mx = fmaxf(mx, __shfl_xor(mx, 16));
    mx = fmaxf(mx, __shfl_xor(mx, 32));
    float sum = 0.f;
    float p[5][4];
#pragma unroll
    for (int kb = 0; kb < 5; kb++)
#pragma unroll
        for (int j = 0; j < 4; j++) {
            int key = kb * 16 + g * 4 + j;
            float pv = (key < S_) ? __expf(sv[kb][j] - mx) : 0.f;
            p[kb][j] = pv;
            sum += pv;
        }
    sum += __shfl_xor(sum, 16);
    sum += __shfl_xor(sum, 32);
    float inv = 1.f / sum;
    // pack P*inv to bf16 and store P[qrow][key]
#pragma unroll
    for (int kb = 0; kb < 5; kb++) {
        unsigned lo = (unsigned)f2bf(p[kb][0] * inv) | ((unsigned)f2bf(p[kb][1] * inv) << 16);
        unsigned hi = (unsigned)f2bf(p[kb][2] * inv) | ((unsigned)f2bf(p[kb][3] * inv) << 16);
        int col = kb * 16 + g * 4;
        *(uint2*)&Ps[qrow * 104 + col] = make_uint2(lo, hi);
    }
    // Y^T = V^T · P^T  (K-dim = 96: keys 77..95 are exact zeros)
    f32x4 ya[4];
#pragma unroll
    for (int mf = 0; mf < 4; mf++) ya[mf] = 0.f;
#pragma unroll
    for (int kk = 0; kk < 3; kk++) {
        int s8 = kk * 4 + g;
        bf16x8 pf = *(const bf16x8*)(Ps + qrow * 104 + s8 * 8);
#pragma unroll
        for (int mf = 0; mf < 4; mf++) {
            bf16x8 vf = *(const bf16x8*)(VT + (mf * 16 + l15) * 104 + s8 * 8);
            ya[mf] = __builtin_amdgcn_mfma_f32_16x16x32_bf16(vf, pf, ya[mf], 0, 0, 0);
        }
    }
    // write Y^T: lane holds d = mf*16 + g*4 + j for its own q-row (col = l15)
    u16* yrow = yt + ((size_t)(n * HW_ + qb * 64 + qrow)) * C_ + h * 64;
#pragma unroll
    for (int mf = 0; mf < 4; mf++) {
        int d0 = mf * 16 + g * 4;
        ushort4 o;
        o.x = f2bf(ya[mf][0]); o.y = f2bf(ya[mf][1]);
        o.z = f2bf(ya[mf][2]); o.w = f2bf(ya[mf][3]);
        *(ushort4*)(yrow + d0) = o;
    }
}

extern "C" void kernel_launch(void* const* d_in, const int* in_sizes, int n_in,
                              void* d_out, int out_size, void* d_ws, size_t ws_size,
                              hipStream_t stream) {
    const float* inp  = (const float*)d_in[0];
    const float* cond = (const float*)d_in[1];
    const float* enc  = (const float*)d_in[2];
    const float* mask = (const float*)d_in[3];
    const float* agw  = (const float*)d_in[4];
    const float* agb  = (const float*)d_in[5];
    const float* lnw  = (const float*)d_in[6];
    const float* lnb  = (const float*)d_in[7];
    const float* qw   = (const float*)d_in[8];
    const float* qb   = (const float*)d_in[9];
    const float* kvw  = (const float*)d_in[10];
    const float* kvb  = (const float*)d_in[11];
    const float* ow   = (const float*)d_in[12];
    const float* ob   = (const float*)d_in[13];
    float* ws  = (float*)d_ws;
    float* out = (float*)d_out;
    u16* wsu = (u16*)((char*)d_ws + WSU_BYTE);

    hipMemsetAsync(ws + WS_STATS, 0, 32 * sizeof(float), stream);
    stats_kernel<<<dim3(N_ * 16), 256, 0, stream>>>(inp, ws + WS_STATS);
    alphabeta_kernel<<<N_, 512, 0, stream>>>(cond, agw, agb, ws + WS_STATS,
                                             ws + WS_ALPHA, ws + WS_BETA);
    qbias_kernel<<<N_, 512, 0, stream>>>(qw, qb, ws + WS_BETA, ws + WS_QBIAS);

    cvt_kernel<<<dim3(C_ * C_ / 1024), 256, 0, stream>>>(qw, wsu + U_QW, C_ * C_ / 4);
    cvt_kernel<<<dim3(C_ * C_ / 1024), 256, 0, stream>>>(ow, wsu + U_OW, C_ * C_ / 4);
    cvt_kernel<<<dim3(1024 * CE_ / 1024), 256, 0, stream>>>(kvw, wsu + U_KVW, 1024 * CE_ / 4);

    xt_kernel<<<dim3(HW_ / 64, C_ / 64, N_), 256, 0, stream>>>(inp, ws + WS_ALPHA, wsu + U_XT);
    ln_kernel<<<dim3(TOK_), 256, 0, stream>>>(enc, lnw, lnb, wsu + U_EB);

    gemm_kv_mfma<<<dim3((TOK_ + 127) / 128, 1024 / 128), 256, 0, stream>>>(
        wsu + U_KVW, wsu + U_EB, kvb, wsu + U_KVB);
    gemm_q_mfma<<<dim3(HW_ / 128, C_ / 128, N_), 256, 0, stream>>>(
        wsu + U_QW, wsu + U_XT, ws + WS_QBIAS, wsu + U_QT);

    attn_mfma<<<dim3(N_ * NH_, HW_ / 64), 256, 0, stream>>>(
        wsu + U_KVB, mask, wsu + U_QT, wsu + U_XT);   // yT aliases xT (consumed)

    gemm_out_mfma<<<dim3(HW_ / 128, C_ / 128, N_), 256, 0, stream>>>(
        wsu + U_OW, wsu + U_XT, ob, inp, out);
}

// Round 5
// 135.196 us; speedup vs baseline: 6.6232x; 1.6166x over previous
//
#include <hip/hip_runtime.h>
#include <math.h>

typedef unsigned short u16;
typedef __bf16 bf16x8 __attribute__((ext_vector_type(8)));
typedef float f32x4 __attribute__((ext_vector_type(4)));

#define AS1 __attribute__((address_space(1)))
#define AS3 __attribute__((address_space(3)))

#define N_    16
#define C_    512
#define HW_   1024
#define CE_   768
#define S_    77
#define NH_   8
#define D_    64
#define FEATS_ 512
#define EPS_  1e-5f
#define TOK_  (N_ * S_)   // 1232

// fp32 workspace (float offsets)
#define WS_STATS 0
#define WS_ALPHA 1024
#define WS_BETA  (WS_ALPHA + 8192)
#define WS_QBIAS (WS_BETA + 8192)
// u16 (bf16) workspace, base at byte 131072
#define WSU_BYTE 131072
#define U_QW  0
#define U_OW  262144
#define U_KVW 524288
#define U_EB  1310720              // 1232*768   = 946176
#define U_KVB 2256896              // 1232*1024  = 1261568
#define U_QT  3518464              // 16*1024*512= 8388608  (ss borrows the first 64KB before gemm_q)
#define U_XT  11907072             // xT, later reused as yT

__device__ __forceinline__ u16 f2bf(float f) {
    unsigned u = __float_as_uint(f);
    return (u16)((u + 0x7FFFu + ((u >> 16) & 1u)) >> 16);
}
__device__ __forceinline__ float bf2f(u16 h) {
    return __uint_as_float(((unsigned)h) << 16);
}

// ---------------- per-sample mean/var partial sums ----------------
__global__ __launch_bounds__(256) void stats_kernel(const float* __restrict__ inp,
                                                    float* __restrict__ stats) {
    int n = blockIdx.x >> 4;
    int slice = blockIdx.x & 15;
    const float* base = inp + (size_t)n * C_ * HW_ + slice * (C_ * HW_ / 16);
    float s = 0.f, s2 = 0.f;
    const float4* b4 = (const float4*)base;
    for (int i = threadIdx.x; i < (C_ * HW_ / 16) / 4; i += 256) {
        float4 v = b4[i];
        s  += v.x + v.y + v.z + v.w;
        s2 += v.x * v.x + v.y * v.y + v.z * v.z + v.w * v.w;
    }
    for (int off = 32; off; off >>= 1) {
        s  += __shfl_down(s, off);
        s2 += __shfl_down(s2, off);
    }
    __shared__ float sh[8];
    int wid = threadIdx.x >> 6, lane = threadIdx.x & 63;
    if (lane == 0) { sh[wid] = s; sh[4 + wid] = s2; }
    __syncthreads();
    if (threadIdx.x == 0) {
        atomicAdd(&stats[2 * n], sh[0] + sh[1] + sh[2] + sh[3]);
        atomicAdd(&stats[2 * n + 1], sh[4] + sh[5] + sh[6] + sh[7]);
    }
}

// ---------------- generic 16xR GEMV: out[n*ostride + r0+r] = bias + dot(X[n], W[r0+r]) ----------------
// X: 16 x 512 (fp32), W: R x 512 (fp32). Block = 16 rows of W x all 16 n. Coalesced LDS-staged.
__global__ __launch_bounds__(256) void gemv16_kernel(const float* __restrict__ X,
                                                     const float* __restrict__ W,
                                                     const float* __restrict__ bias,
                                                     float* __restrict__ out, int ostride) {
    __shared__ float wz[16][512];
    __shared__ float cz[16][512];
    int r0 = blockIdx.x * 16;
    int tid = threadIdx.x;
    for (int i = tid; i < 2048; i += 256) {
        int row = i >> 7, f4 = i & 127;
        *(float4*)&cz[row][f4 * 4] = ((const float4*)(X + (size_t)row * 512))[f4];
        *(float4*)&wz[row][f4 * 4] = ((const float4*)(W + (size_t)(r0 + row) * 512))[f4];
    }
    __syncthreads();
    int n = tid >> 4, r = tid & 15;
    float acc = bias[r0 + r];
    for (int i = 0; i < 128; i++) {
        int j = (r + i) & 127;                 // stagger: cz banks spread, wz broadcasts
        float4 c4 = *(const float4*)&cz[n][j * 4];
        float4 w4 = *(const float4*)&wz[r][j * 4];
        acc += c4.x * w4.x + c4.y * w4.y + c4.z * w4.z + c4.w * w4.w;
    }
    out[(size_t)n * ostride + r0 + r] = acc;
}

// ---------------- fold: ss + stats -> alpha, beta ----------------
__global__ __launch_bounds__(256) void fold_kernel(const float* __restrict__ ss,
                                                   const float* __restrict__ stats,
                                                   float* __restrict__ alpha,
                                                   float* __restrict__ beta) {
    int i = blockIdx.x * 256 + threadIdx.x;    // 0..8191
    int n = i >> 9, c = i & 511;
    float cnt = (float)(C_ * HW_);
    float mu  = stats[2 * n] / cnt;
    float var = stats[2 * n + 1] / cnt - mu * mu;
    float rstd = rsqrtf(var + EPS_);
    float al = rstd * (ss[(size_t)n * 1024 + c] + 1.f);
    alpha[i] = al;
    beta[i]  = ss[(size_t)n * 1024 + 512 + c] - mu * al;
}

// ---------------- fused fp32 -> bf16 weight conversion (qw, ow, kvw) ----------------
__global__ __launch_bounds__(256) void cvt3_kernel(const float* __restrict__ qw,
                                                   const float* __restrict__ ow,
                                                   const float* __restrict__ kvw,
                                                   u16* __restrict__ uq,
                                                   u16* __restrict__ uo,
                                                   u16* __restrict__ ukv) {
    int i = blockIdx.x * 256 + threadIdx.x;    // float4 index, 0..327679
    const float* s; u16* d; int j;
    if (i < 65536)       { s = qw;  d = uq;  j = i; }
    else if (i < 131072) { s = ow;  d = uo;  j = i - 65536; }
    else                 { s = kvw; d = ukv; j = i - 131072; }
    float4 v = ((const float4*)s)[j];
    ushort4 w;
    w.x = f2bf(v.x); w.y = f2bf(v.y); w.z = f2bf(v.z); w.w = f2bf(v.w);
    ((ushort4*)(d))[j] = w;
}

// ---------------- xT[n][hw][c] = input[n][c][hw] * alpha[n][c]  (bf16) ----------------
__global__ __launch_bounds__(256) void xt_kernel(const float* __restrict__ inp,
                                                 const float* __restrict__ alpha,
                                                 u16* __restrict__ xT) {
    int n = blockIdx.z, c0 = blockIdx.y * 64, h0 = blockIdx.x * 64;
    __shared__ float t[64][65];
    int tid = threadIdx.x;
    int rr = tid >> 4, cc = (tid & 15) * 4;
#pragma unroll
    for (int i = 0; i < 4; i++) {
        int cl = rr + i * 16;
        int c = c0 + cl;
        float4 v = *(const float4*)(inp + ((size_t)n * C_ + c) * HW_ + h0 + cc);
        float a = alpha[n * C_ + c];
        t[cl][cc + 0] = v.x * a; t[cl][cc + 1] = v.y * a;
        t[cl][cc + 2] = v.z * a; t[cl][cc + 3] = v.w * a;
    }
    __syncthreads();
#pragma unroll
    for (int i = 0; i < 4; i++) {
        int hl = rr + i * 16;
        ushort4 w;
        w.x = f2bf(t[cc + 0][hl]); w.y = f2bf(t[cc + 1][hl]);
        w.z = f2bf(t[cc + 2][hl]); w.w = f2bf(t[cc + 3][hl]);
        *(ushort4*)(xT + ((size_t)n * HW_ + h0 + hl) * C_ + c0 + cc) = w;
    }
}

// ---------------- layernorm(enc) -> e_b bf16 [token][768] ----------------
__global__ __launch_bounds__(256) void ln_kernel(const float* __restrict__ enc,
                                                 const float* __restrict__ lnw,
                                                 const float* __restrict__ lnb,
                                                 u16* __restrict__ eb) {
    int tok = blockIdx.x;
    const float* row = enc + (size_t)tok * CE_;
    int t = threadIdx.x;
    float v0 = row[t], v1 = row[t + 256], v2 = row[t + 512];
    float sum = v0 + v1 + v2;
    float sq  = v0 * v0 + v1 * v1 + v2 * v2;
    for (int off = 32; off; off >>= 1) {
        sum += __shfl_down(sum, off);
        sq  += __shfl_down(sq, off);
    }
    __shared__ float red[8];
    int wid = t >> 6, lane = t & 63;
    if (lane == 0) { red[wid] = sum; red[4 + wid] = sq; }
    __syncthreads();
    float tot = red[0] + red[1] + red[2] + red[3];
    float tsq = red[4] + red[5] + red[6] + red[7];
    float mu  = tot / CE_;
    float var = tsq / CE_ - mu * mu;
    float rstd = rsqrtf(var + EPS_);
    u16* o = eb + (size_t)tok * CE_;
    o[t]       = f2bf((v0 - mu) * rstd * lnw[t] + lnb[t]);
    o[t + 256] = f2bf((v1 - mu) * rstd * lnw[t + 256] + lnb[t + 256]);
    o[t + 512] = f2bf((v2 - mu) * rstd * lnw[t + 512] + lnb[t + 512]);
}

// ---------------- MFMA GEMM mainloop: C[m][nn] = sum_k A[m][k]*B[nn][k] ----------------
__device__ __forceinline__ void gemm_mainloop(const u16* __restrict__ A, int lda, int arow0,
                                              const u16* __restrict__ B, int ldb, int brow0, int brmax,
                                              int K, f32x4 (&acc)[4][4], u16* As, u16* Bs) {
    int tid = threadIdx.x;
    int lane = tid & 63;
    int wm = ((tid >> 6) >> 1) * 64, wn = ((tid >> 6) & 1) * 64;
    int srow = tid >> 3;                 // 0..31 (+ i*32)
    int sw = (tid & 7) ^ (srow & 7);     // swizzled 16B source slot
    int ldsoff = tid * 8;                // u16 units = 16 B / thread
    for (int kt = 0; kt < K; kt += 64) {
        __syncthreads();
#pragma unroll
        for (int i = 0; i < 4; i++) {
            int ar = arow0 + i * 32 + srow;
            const u16* ga = A + (size_t)ar * lda + kt + sw * 8;
            __builtin_amdgcn_global_load_lds((AS1 void*)ga, (AS3 void*)(As + i * 2048 + ldsoff), 16, 0, 0);
            int br = brow0 + i * 32 + srow; if (br > brmax) br = brmax;
            const u16* gb = B + (size_t)br * ldb + kt + sw * 8;
            __builtin_amdgcn_global_load_lds((AS1 void*)gb, (AS3 void*)(Bs + i * 2048 + ldsoff), 16, 0, 0);
        }
        __syncthreads();
#pragma unroll
        for (int kk = 0; kk < 2; kk++) {
            bf16x8 af[4], bfv[4];
            int ks = kk * 4 + (lane >> 4);
#pragma unroll
            for (int mi = 0; mi < 4; mi++) {
                int r = wm + mi * 16 + (lane & 15);
                af[mi] = *(const bf16x8*)(As + r * 64 + (ks ^ (r & 7)) * 8);
            }
#pragma unroll
            for (int ni = 0; ni < 4; ni++) {
                int r = wn + ni * 16 + (lane & 15);
                bfv[ni] = *(const bf16x8*)(Bs + r * 64 + (ks ^ (r & 7)) * 8);
            }
#pragma unroll
            for (int mi = 0; mi < 4; mi++)
#pragma unroll
                for (int ni = 0; ni < 4; ni++)
                    acc[mi][ni] = __builtin_amdgcn_mfma_f32_16x16x32_bf16(af[mi], bfv[ni], acc[mi][ni], 0, 0, 0);
        }
    }
}

// ---------------- Q GEMM: CT = q_t[n][hw][o] bf16, bias qbias[n][o] ----------------
__global__ __launch_bounds__(256) void gemm_q_mfma(const u16* __restrict__ qwb,
                                                   const u16* __restrict__ xT,
                                                   const float* __restrict__ qbias,
                                                   u16* __restrict__ qt) {
    __shared__ __align__(16) u16 As[128 * 64];
    __shared__ __align__(16) u16 Bs[128 * 64];
    int n = blockIdx.z;
    int arow0 = blockIdx.y * 128, brow0 = blockIdx.x * 128;
    f32x4 acc[4][4];
#pragma unroll
    for (int mi = 0; mi < 4; mi++)
#pragma unroll
        for (int ni = 0; ni < 4; ni++) acc[mi][ni] = 0.f;
    gemm_mainloop(qwb, C_, arow0, xT + (size_t)n * HW_ * C_, C_, brow0, HW_ - 1, C_, acc, As, Bs);
    int lane = threadIdx.x & 63, wid = threadIdx.x >> 6;
    int wm = (wid >> 1) * 64, wn = (wid & 1) * 64;
    u16* CT = qt + (size_t)n * HW_ * C_;
    const float* qb = qbias + n * C_;
#pragma unroll
    for (int mi = 0; mi < 4; mi++) {
        int row = arow0 + wm + mi * 16 + ((lane >> 4) << 2);
        float4 b4 = *(const float4*)(qb + row);
#pragma unroll
        for (int ni = 0; ni < 4; ni++) {
            int col = brow0 + wn + ni * 16 + (lane & 15);
            f32x4 v = acc[mi][ni];
            ushort4 w;
            w.x = f2bf(v.x + b4.x); w.y = f2bf(v.y + b4.y);
            w.z = f2bf(v.z + b4.z); w.w = f2bf(v.w + b4.w);
            *(ushort4*)(CT + (size_t)col * C_ + row) = w;
        }
    }
}

// ---------------- KV GEMM: CT = kv_b[token][j] bf16, bias kvb[j], guard token<1232 ----------------
__global__ __launch_bounds__(256) void gemm_kv_mfma(const u16* __restrict__ kvwb,
                                                    const u16* __restrict__ eb,
                                                    const float* __restrict__ kvbias,
                                                    u16* __restrict__ kvo) {
    __shared__ __align__(16) u16 As[128 * 64];
    __shared__ __align__(16) u16 Bs[128 * 64];
    int arow0 = blockIdx.y * 128, brow0 = blockIdx.x * 128;
    f32x4 acc[4][4];
#pragma unroll
    for (int mi = 0; mi < 4; mi++)
#pragma unroll
        for (int ni = 0; ni < 4; ni++) acc[mi][ni] = 0.f;
    gemm_mainloop(kvwb, CE_, arow0, eb, CE_, brow0, TOK_ - 1, CE_, acc, As, Bs);
    int lane = threadIdx.x & 63, wid = threadIdx.x >> 6;
    int wm = (wid >> 1) * 64, wn = (wid & 1) * 64;
#pragma unroll
    for (int mi = 0; mi < 4; mi++) {
        int row = arow0 + wm + mi * 16 + ((lane >> 4) << 2);
        float4 b4 = *(const float4*)(kvbias + row);
#pragma unroll
        for (int ni = 0; ni < 4; ni++) {
            int col = brow0 + wn + ni * 16 + (lane & 15);
            if (col < TOK_) {
                f32x4 v = acc[mi][ni];
                ushort4 w;
                w.x = f2bf(v.x + b4.x); w.y = f2bf(v.y + b4.y);
                w.z = f2bf(v.z + b4.z); w.w = f2bf(v.w + b4.w);
                *(ushort4*)(kvo + (size_t)col * 1024 + row) = w;
            }
        }
    }
}

// ---------------- OUT GEMM: out[n][o][hw] = acc + ob[o] + input, fp32 ----------------
__global__ __launch_bounds__(256) void gemm_out_mfma(const u16* __restrict__ owb,
                                                     const u16* __restrict__ yT,
                                                     const float* __restrict__ ob,
                                                     const float* __restrict__ inp,
                                                     float* __restrict__ outp) {
    __shared__ __align__(16) u16 As[128 * 64];
    __shared__ __align__(16) u16 Bs[128 * 64];
    int n = blockIdx.z;
    int arow0 = blockIdx.y * 128, brow0 = blockIdx.x * 128;
    f32x4 acc[4][4];
#pragma unroll
    for (int mi = 0; mi < 4; mi++)
#pragma unroll
        for (int ni = 0; ni < 4; ni++) acc[mi][ni] = 0.f;
    gemm_mainloop(owb, C_, arow0, yT + (size_t)n * HW_ * C_, C_, brow0, HW_ - 1, C_, acc, As, Bs);
    int lane = threadIdx.x & 63, wid = threadIdx.x >> 6;
    int wm = (wid >> 1) * 64, wn = (wid & 1) * 64;
    float* Co = outp + (size_t)n * C_ * HW_;
    const float* In = inp + (size_t)n * C_ * HW_;
#pragma unroll
    for (int mi = 0; mi < 4; mi++) {
        int row = arow0 + wm + mi * 16 + ((lane >> 4) << 2);
        float4 b4 = *(const float4*)(ob + row);
#pragma unroll
        for (int ni = 0; ni < 4; ni++) {
            int col = brow0 + wn + ni * 16 + (lane & 15);
            f32x4 v = acc[mi][ni];
            size_t i0 = (size_t)row * HW_ + col;
            Co[i0]            = v.x + b4.x + In[i0];
            Co[i0 + HW_]      = v.y + b4.y + In[i0 + HW_];
            Co[i0 + 2 * HW_]  = v.z + b4.z + In[i0 + 2 * HW_];
            Co[i0 + 3 * HW_]  = v.w + b4.w + In[i0 + 3 * HW_];
        }
    }
}

// ---------------- MFMA attention (swapped-operand): 64 q-rows / block, 4 waves ----------------
__global__ __launch_bounds__(256) void attn_mfma(const u16* __restrict__ kvb,
                                                 const float* __restrict__ mask,
                                                 const u16* __restrict__ qt,
                                                 u16* __restrict__ yt) {
    int nh = blockIdx.x;                  // n*8 + h
    int n = nh >> 3, h = nh & 7;
    int qb = blockIdx.y;                  // 0..15, 64 q-rows each
    __shared__ __align__(16) u16 Qs[64 * 64];
    __shared__ __align__(16) u16 Ks[80 * 64];
    __shared__ __align__(16) u16 VT[64 * 104];
    __shared__ __align__(16) u16 Ps[64 * 104];
    __shared__ float msk[80];
    int tid = threadIdx.x;
    int lane = tid & 63, w = tid >> 6;
    int g = lane >> 4, l15 = lane & 15;

    const u16* qbase = qt + ((size_t)(n * HW_ + qb * 64)) * C_ + h * 64;
#pragma unroll
    for (int pass = 0; pass < 2; pass++) {
        int idx = pass * 256 + tid;
        int row = idx >> 3, slot = idx & 7;
        int sw = slot ^ (row & 7);
        __builtin_amdgcn_global_load_lds((AS1 void*)(qbase + (size_t)row * C_ + sw * 8),
                                         (AS3 void*)(Qs + idx * 8), 16, 0, 0);
    }
    const u16* kbase = kvb + (size_t)(n * S_) * 1024 + h * 64;
#pragma unroll
    for (int pass = 0; pass < 3; pass++) {
        int idx = pass * 256 + tid;
        if (idx < 640) {
            int row = idx >> 3, slot = idx & 7;
            int srow = row < S_ ? row : S_ - 1;
            int sw = slot ^ (row & 7);
            __builtin_amdgcn_global_load_lds((AS1 void*)(kbase + (size_t)srow * 1024 + sw * 8),
                                             (AS3 void*)(Ks + idx * 8), 16, 0, 0);
        }
    }
    {
        int d = tid & 63, sg = tid >> 6;
        const u16* vbase = kvb + (size_t)(n * S_) * 1024 + 512 + h * 64 + d;
        for (int s = sg; s < 104; s += 4) {
            u16 v = (s < S_) ? vbase[(size_t)s * 1024] : (u16)0;
            VT[d * 104 + s] = v;
        }
    }
    for (int i = tid; i < 512; i += 256) {
        int r = i >> 3, cp = i & 7;
        *(unsigned*)&Ps[r * 104 + 80 + cp * 2] = 0u;
    }
    if (tid < 80) msk[tid] = (tid < S_) ? mask[n * S_ + tid] * 10000.f : 0.f;
    __syncthreads();

    int qrow = w * 16 + l15;

    bf16x8 qf[2];
#pragma unroll
    for (int kk = 0; kk < 2; kk++) {
        int s8 = kk * 4 + g;
        qf[kk] = *(const bf16x8*)(Qs + qrow * 64 + (s8 ^ (qrow & 7)) * 8);
    }
    f32x4 sc[5];
#pragma unroll
    for (int kb = 0; kb < 5; kb++) {
        sc[kb] = 0.f;
#pragma unroll
        for (int kk = 0; kk < 2; kk++) {
            int r = kb * 16 + l15;
            int s8 = kk * 4 + g;
            bf16x8 kf = *(const bf16x8*)(Ks + r * 64 + (s8 ^ (r & 7)) * 8);
            sc[kb] = __builtin_amdgcn_mfma_f32_16x16x32_bf16(kf, qf[kk], sc[kb], 0, 0, 0);
        }
    }
    float sv[5][4];
    float mx = -3e38f;
#pragma unroll
    for (int kb = 0; kb < 5; kb++)
#pragma unroll
        for (int j = 0; j < 4; j++) {
            int key = kb * 16 + g * 4 + j;
            float s = sc[kb][j] * 0.125f - msk[key];
            sv[kb][j] = s;
            if (key < S_) mx = fmaxf(mx, s);
        }
    mx = fmaxf(mx, __shfl_xor(mx, 16));
    mx = fmaxf(mx, __shfl_xor(mx, 32));
    float sum = 0.f;
    float p[5][4];
#pragma unroll
    for (int kb = 0; kb < 5; kb++)
#pragma unroll
        for (int j = 0; j < 4; j++) {
            int key = kb * 16 + g * 4 + j;
            float pv = (key < S_) ? __expf(sv[kb][j] - mx) : 0.f;
            p[kb][j] = pv;
            sum += pv;
        }
    sum += __shfl_xor(sum, 16);
    sum += __shfl_xor(sum, 32);
    float inv = 1.f / sum;
#pragma unroll
    for (int kb = 0; kb < 5; kb++) {
        unsigned lo = (unsigned)f2bf(p[kb][0] * inv) | ((unsigned)f2bf(p[kb][1] * inv) << 16);
        unsigned hi = (unsigned)f2bf(p[kb][2] * inv) | ((unsigned)f2bf(p[kb][3] * inv) << 16);
        int col = kb * 16 + g * 4;
        *(uint2*)&Ps[qrow * 104 + col] = make_uint2(lo, hi);
    }
    f32x4 ya[4];
#pragma unroll
    for (int mf = 0; mf < 4; mf++) ya[mf] = 0.f;
#pragma unroll
    for (int kk = 0; kk < 3; kk++) {
        int s8 = kk * 4 + g;
        bf16x8 pf = *(const bf16x8*)(Ps + qrow * 104 + s8 * 8);
#pragma unroll
        for (int mf = 0; mf < 4; mf++) {
            bf16x8 vf = *(const bf16x8*)(VT + (mf * 16 + l15) * 104 + s8 * 8);
            ya[mf] = __builtin_amdgcn_mfma_f32_16x16x32_bf16(vf, pf, ya[mf], 0, 0, 0);
        }
    }
    u16* yrow = yt + ((size_t)(n * HW_ + qb * 64 + qrow)) * C_ + h * 64;
#pragma unroll
    for (int mf = 0; mf < 4; mf++) {
        int d0 = mf * 16 + g * 4;
        ushort4 o;
        o.x = f2bf(ya[mf][0]); o.y = f2bf(ya[mf][1]);
        o.z = f2bf(ya[mf][2]); o.w = f2bf(ya[mf][3]);
        *(ushort4*)(yrow + d0) = o;
    }
}

extern "C" void kernel_launch(void* const* d_in, const int* in_sizes, int n_in,
                              void* d_out, int out_size, void* d_ws, size_t ws_size,
                              hipStream_t stream) {
    const float* inp  = (const float*)d_in[0];
    const float* cond = (const float*)d_in[1];
    const float* enc  = (const float*)d_in[2];
    const float* mask = (const float*)d_in[3];
    const float* agw  = (const float*)d_in[4];
    const float* agb  = (const float*)d_in[5];
    const float* lnw  = (const float*)d_in[6];
    const float* lnb  = (const float*)d_in[7];
    const float* qw   = (const float*)d_in[8];
    const float* qb   = (const float*)d_in[9];
    const float* kvw  = (const float*)d_in[10];
    const float* kvb  = (const float*)d_in[11];
    const float* ow   = (const float*)d_in[12];
    const float* ob   = (const float*)d_in[13];
    float* ws  = (float*)d_ws;
    float* out = (float*)d_out;
    u16* wsu = (u16*)((char*)d_ws + WSU_BYTE);
    float* ssf = (float*)(wsu + U_QT);     // 16x1024 fp32, consumed before gemm_q writes qt

    hipMemsetAsync(ws + WS_STATS, 0, 32 * sizeof(float), stream);
    stats_kernel<<<dim3(N_ * 16), 256, 0, stream>>>(inp, ws + WS_STATS);

    // ss = cond @ adagn_w.T + adagn_b   (1024 rows, 64 blocks)
    gemv16_kernel<<<dim3(64), 256, 0, stream>>>(cond, agw, agb, ssf, 1024);
    fold_kernel<<<dim3(32), 256, 0, stream>>>(ssf, ws + WS_STATS, ws + WS_ALPHA, ws + WS_BETA);
    // qbias = q_b + qw @ beta           (512 rows, 32 blocks)
    gemv16_kernel<<<dim3(32), 256, 0, stream>>>(ws + WS_BETA, qw, qb, ws + WS_QBIAS, 512);

    cvt3_kernel<<<dim3(1280), 256, 0, stream>>>(qw, ow, kvw, wsu + U_QW, wsu + U_OW, wsu + U_KVW);

    xt_kernel<<<dim3(HW_ / 64, C_ / 64, N_), 256, 0, stream>>>(inp, ws + WS_ALPHA, wsu + U_XT);
    ln_kernel<<<dim3(TOK_), 256, 0, stream>>>(enc, lnw, lnb, wsu + U_EB);

    gemm_kv_mfma<<<dim3((TOK_ + 127) / 128, 1024 / 128), 256, 0, stream>>>(
        wsu + U_KVW, wsu + U_EB, kvb, wsu + U_KVB);
    gemm_q_mfma<<<dim3(HW_ / 128, C_ / 128, N_), 256, 0, stream>>>(
        wsu + U_QW, wsu + U_XT, ws + WS_QBIAS, wsu + U_QT);

    attn_mfma<<<dim3(N_ * NH_, HW_ / 64), 256, 0, stream>>>(
        wsu + U_KVB, mask, wsu + U_QT, wsu + U_XT);   // yT aliases xT (consumed)

    gemm_out_mfma<<<dim3(HW_ / 128, C_ / 128, N_), 256, 0, stream>>>(
        wsu + U_OW, wsu + U_XT, ob, inp, out);
}

// Round 6
// 111.803 us; speedup vs baseline: 8.0090x; 1.2092x over previous
//
#include <hip/hip_runtime.h>
#include <math.h>

typedef unsigned short u16;
typedef __bf16 bf16x8 __attribute__((ext_vector_type(8)));
typedef float f32x4 __attribute__((ext_vector_type(4)));

#define AS1 __attribute__((address_space(1)))
#define AS3 __attribute__((address_space(3)))

#define N_    16
#define C_    512
#define HW_   1024
#define CE_   768
#define S_    77
#define NH_   8
#define D_    64
#define FEATS_ 512
#define EPS_  1e-5f
#define TOK_  (N_ * S_)   // 1232

// fp32 workspace (float offsets)
#define WS_PSTAT 0                  // 256 blocks x 2 partials
#define WS_QBIAS 1024               // 16*512
// u16 (bf16) workspace, base at byte 131072
#define WSU_BYTE 131072
#define U_QW  0
#define U_OW  262144
#define U_KVW 524288
#define U_EB  1310720              // 1232*768
#define U_KVB 2256896              // 1232*1024
#define U_QT  3518464              // 16*1024*512 (ssf borrows first 64KB until mega3)
#define U_XT  11907072             // xT, later reused as yT

__device__ __forceinline__ u16 f2bf(float f) {
    unsigned u = __float_as_uint(f);
    return (u16)((u + 0x7FFFu + ((u >> 16) & 1u)) >> 16);
}
__device__ __forceinline__ float bf2f(u16 h) {
    return __uint_as_float(((unsigned)h) << 16);
}

// ================= MEGA 1: stats partials | weight cvt | LN(enc) | gemv ss =================
__global__ __launch_bounds__(256) void mega1_kernel(const float* __restrict__ inp,
                                                    float* __restrict__ pstats,
                                                    const float* __restrict__ qw,
                                                    const float* __restrict__ ow,
                                                    const float* __restrict__ kvw,
                                                    u16* __restrict__ uq,
                                                    u16* __restrict__ uo,
                                                    u16* __restrict__ ukv,
                                                    const float* __restrict__ enc,
                                                    const float* __restrict__ lnw,
                                                    const float* __restrict__ lnb,
                                                    u16* __restrict__ eb,
                                                    const float* __restrict__ cond,
                                                    const float* __restrict__ agw,
                                                    const float* __restrict__ agb,
                                                    float* __restrict__ ssf) {
    int bid = blockIdx.x;
    int tid = threadIdx.x;
    if (bid < 256) {
        // ---- stats: per-block partial sum/sumsq (no atomics) ----
        int n = bid >> 4, slice = bid & 15;
        const float* base = inp + (size_t)n * C_ * HW_ + slice * (C_ * HW_ / 16);
        float s = 0.f, s2 = 0.f;
        const float4* b4 = (const float4*)base;
        for (int i = tid; i < (C_ * HW_ / 16) / 4; i += 256) {
            float4 v = b4[i];
            s  += v.x + v.y + v.z + v.w;
            s2 += v.x * v.x + v.y * v.y + v.z * v.z + v.w * v.w;
        }
        for (int off = 32; off; off >>= 1) {
            s  += __shfl_down(s, off);
            s2 += __shfl_down(s2, off);
        }
        __shared__ float sh[8];
        int wid = tid >> 6, lane = tid & 63;
        if (lane == 0) { sh[wid] = s; sh[4 + wid] = s2; }
        __syncthreads();
        if (tid == 0) {
            pstats[bid * 2]     = sh[0] + sh[1] + sh[2] + sh[3];
            pstats[bid * 2 + 1] = sh[4] + sh[5] + sh[6] + sh[7];
        }
    } else if (bid < 1536) {
        // ---- cvt3: fp32 -> bf16 weights ----
        int i = (bid - 256) * 256 + tid;
        const float* s; u16* d; int j;
        if (i < 65536)       { s = qw;  d = uq;  j = i; }
        else if (i < 131072) { s = ow;  d = uo;  j = i - 65536; }
        else                 { s = kvw; d = ukv; j = i - 131072; }
        float4 v = ((const float4*)s)[j];
        ushort4 w;
        w.x = f2bf(v.x); w.y = f2bf(v.y); w.z = f2bf(v.z); w.w = f2bf(v.w);
        ((ushort4*)(d))[j] = w;
    } else if (bid < 2768) {
        // ---- layernorm(enc) -> eb bf16 ----
        int tok = bid - 1536;
        const float* row = enc + (size_t)tok * CE_;
        int t = tid;
        float v0 = row[t], v1 = row[t + 256], v2 = row[t + 512];
        float sum = v0 + v1 + v2;
        float sq  = v0 * v0 + v1 * v1 + v2 * v2;
        for (int off = 32; off; off >>= 1) {
            sum += __shfl_down(sum, off);
            sq  += __shfl_down(sq, off);
        }
        __shared__ float red[8];
        int wid = t >> 6, lane = t & 63;
        if (lane == 0) { red[wid] = sum; red[4 + wid] = sq; }
        __syncthreads();
        float tot = red[0] + red[1] + red[2] + red[3];
        float tsq = red[4] + red[5] + red[6] + red[7];
        float mu  = tot / CE_;
        float var = tsq / CE_ - mu * mu;
        float rstd = rsqrtf(var + EPS_);
        u16* o = eb + (size_t)tok * CE_;
        o[t]       = f2bf((v0 - mu) * rstd * lnw[t] + lnb[t]);
        o[t + 256] = f2bf((v1 - mu) * rstd * lnw[t + 256] + lnb[t + 256]);
        o[t + 512] = f2bf((v2 - mu) * rstd * lnw[t + 512] + lnb[t + 512]);
    } else {
        // ---- gemv_ss: ssf[n][r] = agb[r] + dot(cond[n], agw[r]) ----
        __shared__ float wz[16][512];
        __shared__ float cz[16][512];
        int r0 = (bid - 2768) * 16;
        for (int i = tid; i < 2048; i += 256) {
            int row = i >> 7, f4 = i & 127;
            *(float4*)&cz[row][f4 * 4] = ((const float4*)(cond + (size_t)row * 512))[f4];
            *(float4*)&wz[row][f4 * 4] = ((const float4*)(agw + (size_t)(r0 + row) * 512))[f4];
        }
        __syncthreads();
        int n = tid >> 4, r = tid & 15;
        float acc = agb[r0 + r];
        for (int i = 0; i < 128; i++) {
            int j = (r + i) & 127;
            float4 c4 = *(const float4*)&cz[n][j * 4];
            float4 w4 = *(const float4*)&wz[r][j * 4];
            acc += c4.x * w4.x + c4.y * w4.y + c4.z * w4.z + c4.w * w4.w;
        }
        ssf[(size_t)n * 1024 + r0 + r] = acc;
    }
}

// ================= MEGA 2: xT (alpha inline) | gemv qbias (beta inline) =================
__global__ __launch_bounds__(256) void mega2_kernel(const float* __restrict__ inp,
                                                    const float* __restrict__ ssf,
                                                    const float* __restrict__ pstats,
                                                    u16* __restrict__ xT,
                                                    const float* __restrict__ qw,
                                                    const float* __restrict__ qb,
                                                    float* __restrict__ qbias) {
    int bid = blockIdx.x;
    int tid = threadIdx.x;
    float cnt = (float)(C_ * HW_);
    if (bid < 2048) {
        // ---- xT[n][hw][c] = input[n][c][hw] * alpha[n][c] ----
        int n = bid >> 7, rem = bid & 127;
        int c0 = (rem >> 4) * 64, h0 = (rem & 15) * 64;
        float s = 0.f, s2 = 0.f;
        for (int k = 0; k < 16; k++) {
            s  += pstats[(n * 16 + k) * 2];
            s2 += pstats[(n * 16 + k) * 2 + 1];
        }
        float mu = s / cnt;
        float rstd = rsqrtf(s2 / cnt - mu * mu + EPS_);
        __shared__ float t[64][65];
        int rr = tid >> 4, cc = (tid & 15) * 4;
#pragma unroll
        for (int i = 0; i < 4; i++) {
            int cl = rr + i * 16;
            int c = c0 + cl;
            float a = rstd * (ssf[(size_t)n * 1024 + c] + 1.f);
            float4 v = *(const float4*)(inp + ((size_t)n * C_ + c) * HW_ + h0 + cc);
            t[cl][cc + 0] = v.x * a; t[cl][cc + 1] = v.y * a;
            t[cl][cc + 2] = v.z * a; t[cl][cc + 3] = v.w * a;
        }
        __syncthreads();
#pragma unroll
        for (int i = 0; i < 4; i++) {
            int hl = rr + i * 16;
            ushort4 w;
            w.x = f2bf(t[cc + 0][hl]); w.y = f2bf(t[cc + 1][hl]);
            w.z = f2bf(t[cc + 2][hl]); w.w = f2bf(t[cc + 3][hl]);
            *(ushort4*)(xT + ((size_t)n * HW_ + h0 + hl) * C_ + c0 + cc) = w;
        }
    } else {
        // ---- qbias[n][r] = qb[r] + dot(beta[n], qw[r]); beta computed inline ----
        __shared__ float wz[16][512];
        __shared__ float cz[16][512];
        __shared__ float muS[16], rsS[16];
        int r0 = (bid - 2048) * 16;
        if (tid < 16) {
            float s = 0.f, s2 = 0.f;
            for (int k = 0; k < 16; k++) {
                s  += pstats[(tid * 16 + k) * 2];
                s2 += pstats[(tid * 16 + k) * 2 + 1];
            }
            float mu = s / cnt;
            muS[tid] = mu;
            rsS[tid] = rsqrtf(s2 / cnt - mu * mu + EPS_);
        }
        __syncthreads();
        for (int i = tid; i < 2048; i += 256) {
            int row = i >> 7, f4 = i & 127;
            float4 sc4 = ((const float4*)(ssf + (size_t)row * 1024))[f4];
            float4 sh4 = ((const float4*)(ssf + (size_t)row * 1024 + 512))[f4];
            float mu = muS[row], rs = rsS[row];
            float4 b;
            b.x = sh4.x - mu * (rs * (sc4.x + 1.f));
            b.y = sh4.y - mu * (rs * (sc4.y + 1.f));
            b.z = sh4.z - mu * (rs * (sc4.z + 1.f));
            b.w = sh4.w - mu * (rs * (sc4.w + 1.f));
            *(float4*)&cz[row][f4 * 4] = b;
            *(float4*)&wz[row][f4 * 4] = ((const float4*)(qw + (size_t)(r0 + row) * 512))[f4];
        }
        __syncthreads();
        int n = tid >> 4, r = tid & 15;
        float acc = qb[r0 + r];
        for (int i = 0; i < 128; i++) {
            int j = (r + i) & 127;
            float4 c4 = *(const float4*)&cz[n][j * 4];
            float4 w4 = *(const float4*)&wz[r][j * 4];
            acc += c4.x * w4.x + c4.y * w4.y + c4.z * w4.z + c4.w * w4.w;
        }
        qbias[(size_t)n * 512 + r0 + r] = acc;
    }
}

// ---------------- MFMA GEMM mainloop (shared by mega3) ----------------
__device__ __forceinline__ void gemm_mainloop(const u16* __restrict__ A, int lda, int arow0,
                                              const u16* __restrict__ B, int ldb, int brow0, int brmax,
                                              int K, f32x4 (&acc)[4][4], u16* As, u16* Bs) {
    int tid = threadIdx.x;
    int lane = tid & 63;
    int wm = ((tid >> 6) >> 1) * 64, wn = ((tid >> 6) & 1) * 64;
    int srow = tid >> 3;
    int sw = (tid & 7) ^ (srow & 7);
    int ldsoff = tid * 8;
    for (int kt = 0; kt < K; kt += 64) {
        __syncthreads();
#pragma unroll
        for (int i = 0; i < 4; i++) {
            int ar = arow0 + i * 32 + srow;
            const u16* ga = A + (size_t)ar * lda + kt + sw * 8;
            __builtin_amdgcn_global_load_lds((AS1 void*)ga, (AS3 void*)(As + i * 2048 + ldsoff), 16, 0, 0);
            int br = brow0 + i * 32 + srow; if (br > brmax) br = brmax;
            const u16* gb = B + (size_t)br * ldb + kt + sw * 8;
            __builtin_amdgcn_global_load_lds((AS1 void*)gb, (AS3 void*)(Bs + i * 2048 + ldsoff), 16, 0, 0);
        }
        __syncthreads();
#pragma unroll
        for (int kk = 0; kk < 2; kk++) {
            bf16x8 af[4], bfv[4];
            int ks = kk * 4 + (lane >> 4);
#pragma unroll
            for (int mi = 0; mi < 4; mi++) {
                int r = wm + mi * 16 + (lane & 15);
                af[mi] = *(const bf16x8*)(As + r * 64 + (ks ^ (r & 7)) * 8);
            }
#pragma unroll
            for (int ni = 0; ni < 4; ni++) {
                int r = wn + ni * 16 + (lane & 15);
                bfv[ni] = *(const bf16x8*)(Bs + r * 64 + (ks ^ (r & 7)) * 8);
            }
#pragma unroll
            for (int mi = 0; mi < 4; mi++)
#pragma unroll
                for (int ni = 0; ni < 4; ni++)
                    acc[mi][ni] = __builtin_amdgcn_mfma_f32_16x16x32_bf16(af[mi], bfv[ni], acc[mi][ni], 0, 0, 0);
        }
    }
}

// ================= MEGA 3: Q GEMM (512 blocks) | KV GEMM (80 blocks) =================
__global__ __launch_bounds__(256) void mega3_kernel(const u16* __restrict__ qwb,
                                                    const u16* __restrict__ xT,
                                                    const float* __restrict__ qbias,
                                                    u16* __restrict__ qt,
                                                    const u16* __restrict__ kvwb,
                                                    const u16* __restrict__ eb,
                                                    const float* __restrict__ kvbias,
                                                    u16* __restrict__ kvo) {
    __shared__ __align__(16) u16 As[128 * 64];
    __shared__ __align__(16) u16 Bs[128 * 64];
    int bid = blockIdx.x;
    int lane = threadIdx.x & 63, wid = threadIdx.x >> 6;
    int wm = (wid >> 1) * 64, wn = (wid & 1) * 64;
    f32x4 acc[4][4];
#pragma unroll
    for (int mi = 0; mi < 4; mi++)
#pragma unroll
        for (int ni = 0; ni < 4; ni++) acc[mi][ni] = 0.f;

    if (bid < 512) {
        int n = bid >> 5, r = bid & 31;
        int brow0 = (r & 7) * 128, arow0 = (r >> 3) * 128;
        gemm_mainloop(qwb, C_, arow0, xT + (size_t)n * HW_ * C_, C_, brow0, HW_ - 1, C_, acc, As, Bs);
        u16* CT = qt + (size_t)n * HW_ * C_;
        const float* qbn = qbias + n * C_;
#pragma unroll
        for (int mi = 0; mi < 4; mi++) {
            int row = arow0 + wm + mi * 16 + ((lane >> 4) << 2);
            float4 b4 = *(const float4*)(qbn + row);
#pragma unroll
            for (int ni = 0; ni < 4; ni++) {
                int col = brow0 + wn + ni * 16 + (lane & 15);
                f32x4 v = acc[mi][ni];
                ushort4 w;
                w.x = f2bf(v.x + b4.x); w.y = f2bf(v.y + b4.y);
                w.z = f2bf(v.z + b4.z); w.w = f2bf(v.w + b4.w);
                *(ushort4*)(CT + (size_t)col * C_ + row) = w;
            }
        }
    } else {
        int t = bid - 512;
        int brow0 = (t % 10) * 128, arow0 = (t / 10) * 128;
        gemm_mainloop(kvwb, CE_, arow0, eb, CE_, brow0, TOK_ - 1, CE_, acc, As, Bs);
#pragma unroll
        for (int mi = 0; mi < 4; mi++) {
            int row = arow0 + wm + mi * 16 + ((lane >> 4) << 2);
            float4 b4 = *(const float4*)(kvbias + row);
#pragma unroll
            for (int ni = 0; ni < 4; ni++) {
                int col = brow0 + wn + ni * 16 + (lane & 15);
                if (col < TOK_) {
                    f32x4 v = acc[mi][ni];
                    ushort4 w;
                    w.x = f2bf(v.x + b4.x); w.y = f2bf(v.y + b4.y);
                    w.z = f2bf(v.z + b4.z); w.w = f2bf(v.w + b4.w);
                    *(ushort4*)(kvo + (size_t)col * 1024 + row) = w;
                }
            }
        }
    }
}

// ---------------- OUT GEMM: out[n][o][hw] = acc + ob[o] + input, fp32 ----------------
__global__ __launch_bounds__(256) void gemm_out_mfma(const u16* __restrict__ owb,
                                                     const u16* __restrict__ yT,
                                                     const float* __restrict__ ob,
                                                     const float* __restrict__ inp,
                                                     float* __restrict__ outp) {
    __shared__ __align__(16) u16 As[128 * 64];
    __shared__ __align__(16) u16 Bs[128 * 64];
    int n = blockIdx.z;
    int arow0 = blockIdx.y * 128, brow0 = blockIdx.x * 128;
    f32x4 acc[4][4];
#pragma unroll
    for (int mi = 0; mi < 4; mi++)
#pragma unroll
        for (int ni = 0; ni < 4; ni++) acc[mi][ni] = 0.f;
    gemm_mainloop(owb, C_, arow0, yT + (size_t)n * HW_ * C_, C_, brow0, HW_ - 1, C_, acc, As, Bs);
    int lane = threadIdx.x & 63, wid = threadIdx.x >> 6;
    int wm = (wid >> 1) * 64, wn = (wid & 1) * 64;
    float* Co = outp + (size_t)n * C_ * HW_;
    const float* In = inp + (size_t)n * C_ * HW_;
#pragma unroll
    for (int mi = 0; mi < 4; mi++) {
        int row = arow0 + wm + mi * 16 + ((lane >> 4) << 2);
        float4 b4 = *(const float4*)(ob + row);
#pragma unroll
        for (int ni = 0; ni < 4; ni++) {
            int col = brow0 + wn + ni * 16 + (lane & 15);
            f32x4 v = acc[mi][ni];
            size_t i0 = (size_t)row * HW_ + col;
            Co[i0]            = v.x + b4.x + In[i0];
            Co[i0 + HW_]      = v.y + b4.y + In[i0 + HW_];
            Co[i0 + 2 * HW_]  = v.z + b4.z + In[i0 + 2 * HW_];
            Co[i0 + 3 * HW_]  = v.w + b4.w + In[i0 + 3 * HW_];
        }
    }
}

// ---------------- MFMA attention (swapped-operand): 64 q-rows / block, 4 waves ----------------
__global__ __launch_bounds__(256) void attn_mfma(const u16* __restrict__ kvb,
                                                 const float* __restrict__ mask,
                                                 const u16* __restrict__ qt,
                                                 u16* __restrict__ yt) {
    int nh = blockIdx.x;
    int n = nh >> 3, h = nh & 7;
    int qb = blockIdx.y;
    __shared__ __align__(16) u16 Qs[64 * 64];
    __shared__ __align__(16) u16 Ks[80 * 64];
    __shared__ __align__(16) u16 VT[64 * 104];
    __shared__ __align__(16) u16 Ps[64 * 104];
    __shared__ float msk[80];
    int tid = threadIdx.x;
    int lane = tid & 63, w = tid >> 6;
    int g = lane >> 4, l15 = lane & 15;

    const u16* qbase = qt + ((size_t)(n * HW_ + qb * 64)) * C_ + h * 64;
#pragma unroll
    for (int pass = 0; pass < 2; pass++) {
        int idx = pass * 256 + tid;
        int row = idx >> 3, slot = idx & 7;
        int sw = slot ^ (row & 7);
        __builtin_amdgcn_global_load_lds((AS1 void*)(qbase + (size_t)row * C_ + sw * 8),
                                         (AS3 void*)(Qs + idx * 8), 16, 0, 0);
    }
    const u16* kbase = kvb + (size_t)(n * S_) * 1024 + h * 64;
#pragma unroll
    for (int pass = 0; pass < 3; pass++) {
        int idx = pass * 256 + tid;
        if (idx < 640) {
            int row = idx >> 3, slot = idx & 7;
            int srow = row < S_ ? row : S_ - 1;
            int sw = slot ^ (row & 7);
            __builtin_amdgcn_global_load_lds((AS1 void*)(kbase + (size_t)srow * 1024 + sw * 8),
                                             (AS3 void*)(Ks + idx * 8), 16, 0, 0);
        }
    }
    {
        int d = tid & 63, sg = tid >> 6;
        const u16* vbase = kvb + (size_t)(n * S_) * 1024 + 512 + h * 64 + d;
        for (int s = sg; s < 104; s += 4) {
            u16 v = (s < S_) ? vbase[(size_t)s * 1024] : (u16)0;
            VT[d * 104 + s] = v;
        }
    }
    for (int i = tid; i < 512; i += 256) {
        int r = i >> 3, cp = i & 7;
        *(unsigned*)&Ps[r * 104 + 80 + cp * 2] = 0u;
    }
    if (tid < 80) msk[tid] = (tid < S_) ? mask[n * S_ + tid] * 10000.f : 0.f;
    __syncthreads();

    int qrow = w * 16 + l15;

    bf16x8 qf[2];
#pragma unroll
    for (int kk = 0; kk < 2; kk++) {
        int s8 = kk * 4 + g;
        qf[kk] = *(const bf16x8*)(Qs + qrow * 64 + (s8 ^ (qrow & 7)) * 8);
    }
    f32x4 sc[5];
#pragma unroll
    for (int kb = 0; kb < 5; kb++) {
        sc[kb] = 0.f;
#pragma unroll
        for (int kk = 0; kk < 2; kk++) {
            int r = kb * 16 + l15;
            int s8 = kk * 4 + g;
            bf16x8 kf = *(const bf16x8*)(Ks + r * 64 + (s8 ^ (r & 7)) * 8);
            sc[kb] = __builtin_amdgcn_mfma_f32_16x16x32_bf16(kf, qf[kk], sc[kb], 0, 0, 0);
        }
    }
    float sv[5][4];
    float mx = -3e38f;
#pragma unroll
    for (int kb = 0; kb < 5; kb++)
#pragma unroll
        for (int j = 0; j < 4; j++) {
            int key = kb * 16 + g * 4 + j;
            float s = sc[kb][j] * 0.125f - msk[key];
            sv[kb][j] = s;
            if (key < S_) mx = fmaxf(mx, s);
        }
    mx = fmaxf(mx, __shfl_xor(mx, 16));
    mx = fmaxf(mx, __shfl_xor(mx, 32));
    float sum = 0.f;
    float p[5][4];
#pragma unroll
    for (int kb = 0; kb < 5; kb++)
#pragma unroll
        for (int j = 0; j < 4; j++) {
            int key = kb * 16 + g * 4 + j;
            float pv = (key < S_) ? __expf(sv[kb][j] - mx) : 0.f;
            p[kb][j] = pv;
            sum += pv;
        }
    sum += __shfl_xor(sum, 16);
    sum += __shfl_xor(sum, 32);
    float inv = 1.f / sum;
#pragma unroll
    for (int kb = 0; kb < 5; kb++) {
        unsigned lo = (unsigned)f2bf(p[kb][0] * inv) | ((unsigned)f2bf(p[kb][1] * inv) << 16);
        unsigned hi = (unsigned)f2bf(p[kb][2] * inv) | ((unsigned)f2bf(p[kb][3] * inv) << 16);
        int col = kb * 16 + g * 4;
        *(uint2*)&Ps[qrow * 104 + col] = make_uint2(lo, hi);
    }
    f32x4 ya[4];
#pragma unroll
    for (int mf = 0; mf < 4; mf++) ya[mf] = 0.f;
#pragma unroll
    for (int kk = 0; kk < 3; kk++) {
        int s8 = kk * 4 + g;
        bf16x8 pf = *(const bf16x8*)(Ps + qrow * 104 + s8 * 8);
#pragma unroll
        for (int mf = 0; mf < 4; mf++) {
            bf16x8 vf = *(const bf16x8*)(VT + (mf * 16 + l15) * 104 + s8 * 8);
            ya[mf] = __builtin_amdgcn_mfma_f32_16x16x32_bf16(vf, pf, ya[mf], 0, 0, 0);
        }
    }
    u16* yrow = yt + ((size_t)(n * HW_ + qb * 64 + qrow)) * C_ + h * 64;
#pragma unroll
    for (int mf = 0; mf < 4; mf++) {
        int d0 = mf * 16 + g * 4;
        ushort4 o;
        o.x = f2bf(ya[mf][0]); o.y = f2bf(ya[mf][1]);
        o.z = f2bf(ya[mf][2]); o.w = f2bf(ya[mf][3]);
        *(ushort4*)(yrow + d0) = o;
    }
}

extern "C" void kernel_launch(void* const* d_in, const int* in_sizes, int n_in,
                              void* d_out, int out_size, void* d_ws, size_t ws_size,
                              hipStream_t stream) {
    const float* inp  = (const float*)d_in[0];
    const float* cond = (const float*)d_in[1];
    const float* enc  = (const float*)d_in[2];
    const float* mask = (const float*)d_in[3];
    const float* agw  = (const float*)d_in[4];
    const float* agb  = (const float*)d_in[5];
    const float* lnw  = (const float*)d_in[6];
    const float* lnb  = (const float*)d_in[7];
    const float* qw   = (const float*)d_in[8];
    const float* qb   = (const float*)d_in[9];
    const float* kvw  = (const float*)d_in[10];
    const float* kvb  = (const float*)d_in[11];
    const float* ow   = (const float*)d_in[12];
    const float* ob   = (const float*)d_in[13];
    float* ws  = (float*)d_ws;
    float* out = (float*)d_out;
    u16* wsu = (u16*)((char*)d_ws + WSU_BYTE);
    float* ssf = (float*)(wsu + U_QT);     // 16x1024 fp32, consumed before mega3 writes qt

    // mega1: stats(256) | cvt3(1280) | ln(1232) | gemv_ss(64)  = 2832 blocks
    mega1_kernel<<<dim3(2832), 256, 0, stream>>>(inp, ws + WS_PSTAT,
                                                 qw, ow, kvw, wsu + U_QW, wsu + U_OW, wsu + U_KVW,
                                                 enc, lnw, lnb, wsu + U_EB,
                                                 cond, agw, agb, ssf);
    // mega2: xT(2048) | qbias(32) = 2080 blocks
    mega2_kernel<<<dim3(2080), 256, 0, stream>>>(inp, ssf, ws + WS_PSTAT,
                                                 wsu + U_XT, qw, qb, ws + WS_QBIAS);
    // mega3: gemm_q(512) | gemm_kv(80) = 592 blocks
    mega3_kernel<<<dim3(592), 256, 0, stream>>>(wsu + U_QW, wsu + U_XT, ws + WS_QBIAS, wsu + U_QT,
                                                wsu + U_KVW, wsu + U_EB, kvb, wsu + U_KVB);

    attn_mfma<<<dim3(N_ * NH_, HW_ / 64), 256, 0, stream>>>(
        wsu + U_KVB, mask, wsu + U_QT, wsu + U_XT);   // yT aliases xT (consumed)

    gemm_out_mfma<<<dim3(HW_ / 128, C_ / 128, N_), 256, 0, stream>>>(
        wsu + U_OW, wsu + U_XT, ob, inp, out);
}